// Round 12
// baseline (234.112 us; speedup 1.0000x reference)
//
#include <hip/hip_runtime.h>
#include <hip/hip_bf16.h>
#include <math.h>

// Problem constants
#define B_N 4096
#define BITSN 64
#define HID 512
#define EPSV 1e-5f
#define BT 16   // batch rows per shift2 block

typedef unsigned short ushort_t;
typedef __attribute__((ext_vector_type(8))) short bf16x8;
typedef __attribute__((ext_vector_type(4))) float f32x4;
typedef __attribute__((ext_vector_type(16))) float f32x16;

__device__ __forceinline__ ushort_t f2bf(float f) {
  unsigned u = __float_as_uint(f);
  u += 0x7FFF + ((u >> 16) & 1);   // round-to-nearest-even
  return (ushort_t)(u >> 16);
}

__device__ __forceinline__ unsigned pack2bf(float lo, float hi) {
  union { __hip_bfloat162 h; unsigned u; } cv;
  cv.h = __float22bfloat162_rn(make_float2(lo, hi));  // v_cvt_pk_bf16_f32
  return cv.u;
}

__device__ __forceinline__ float bf2f(short v) {
  return __uint_as_float(((unsigned)(unsigned short)v) << 16);
}

// ---------------- prep: bf16 copies, transposes, FRAGMENT-ORDER weights ----
// Wi2f32: 32x32x16 frag order (big GEMM1 B). Frag (ks 0..31, ct 0..15) lane l:
//   Wi2[ct*32 + (l&31)][ks*16 + (l>>5)*8 + j].
// W2f: 16x16x32 frag order (shift2 GEMM2 B, verified R5/R10).
// Wi3f: 16x16x32 frag order (big GEMM2 B, verified R5/R11).
// Wi1posTb: bf16 pos_part transpose [64][512].
__global__ __launch_bounds__(256) void prep_kernel(
    const float* __restrict__ Wi2, const float* __restrict__ Wi3,
    const float* __restrict__ Wi1, const float* __restrict__ W1,
    const float* __restrict__ W2, const float* __restrict__ W3,
    ushort_t* __restrict__ Wi1posTb, ushort_t* __restrict__ W1b,
    ushort_t* __restrict__ W2f, ushort_t* __restrict__ W3b,
    ushort_t* __restrict__ Wi1sb, ushort_t* __restrict__ Wi2f32,
    ushort_t* __restrict__ Wi3f) {
  int idx = blockIdx.x * 256 + threadIdx.x;
  if (idx < 512 * 512) {
    // W2f (16x16x32 frag order) for shift2 GEMM2
    {
      int j = idx & 7, lane = (idx >> 3) & 63;
      int ct = (idx >> 9) & 31, ks = idx >> 14;
      int c = ct * 16 + (lane & 15);
      int k = ks * 32 + (lane >> 4) * 8 + j;
      W2f[idx] = f2bf(W2[c * 512 + k]);
    }
    // Wi2f32 (32x32x16 frag order) for big GEMM1
    {
      int j = idx & 7, lane = (idx >> 3) & 63;
      int ct = (idx >> 9) & 15, ks = idx >> 13;
      int c = ct * 32 + (lane & 31);
      int k = ks * 16 + (lane >> 5) * 8 + j;
      Wi2f32[idx] = f2bf(Wi2[c * 512 + k]);
    }
  }
  if (idx < 64 * 512) {
    W3b[idx] = f2bf(W3[idx]);
    int p = idx >> 9, i = idx & 511;
    Wi1posTb[idx] = f2bf(Wi1[i * 128 + p]);   // pos_part[p][i] = Wi1[i][p], bf16
    // Wi3f frag-order (16x16x32), verified R5
    int j = idx & 7, lane = (idx >> 3) & 63;
    int nt = (idx >> 9) & 3, ks2 = idx >> 11;
    int jr = nt * 16 + (lane & 15);
    int k = ks2 * 32 + (lane >> 4) * 8 + j;
    Wi3f[idx] = f2bf(Wi3[jr * 512 + k]);
  }
  if (idx < 512 * 64) {
    W1b[idx] = f2bf(W1[idx]);                       // [512][64]
    int j = idx >> 6, k = idx & 63;
    Wi1sb[idx] = f2bf(Wi1[j * 128 + 64 + k]);       // shift cols of Wi1: [512][64]
  }
}

// ---------------- shift decoder, MFMA-batched: 16 rows/block ----------------
__global__ __launch_bounds__(256) void shift2_kernel(
    const float* __restrict__ shift_bits,
    const ushort_t* __restrict__ W1b, const float* __restrict__ b1,
    const float* __restrict__ g1, const float* __restrict__ be1,
    const ushort_t* __restrict__ W2f, const float* __restrict__ b2,
    const float* __restrict__ g2, const float* __restrict__ be2,
    const ushort_t* __restrict__ W3b, const float* __restrict__ b3,
    const ushort_t* __restrict__ Wi1sb, const float* __restrict__ bi1,
    float* __restrict__ sp) {
  __shared__ __align__(16) ushort_t hA[BT * 512];     // 16KB: h1 (post LN1+relu)
  __shared__ __align__(16) char reg2[32 * 1024];      // phase union
  __shared__ float b1s[512], g1s[512], be1s[512];
  __shared__ float b2s[512], g2s[512], be2s[512], bi1s[512];
  __shared__ float red[4][BT][2];
  __shared__ float b3s[64];

  ushort_t* sbt = (ushort_t*)reg2;                    // phase 1: shift_bits tile [16][64]
  ushort_t* h2  = (ushort_t*)reg2;                    // phase 3: h2 [16][512]
  float (*lg32)[68] = (float(*)[68])(reg2 + 16 * 1024);
  ushort_t* sb2 = (ushort_t*)(reg2 + 16 * 1024 + 16 * 68 * 4);  // soft [16][64]

  int b0 = blockIdx.x * BT;
  int t = threadIdx.x, w = t >> 6, l = t & 63, lg = l >> 4, l15 = l & 15;

  b1s[t] = b1[t];  b1s[t + 256] = b1[t + 256];
  g1s[t] = g1[t];  g1s[t + 256] = g1[t + 256];
  be1s[t] = be1[t]; be1s[t + 256] = be1[t + 256];
  b2s[t] = b2[t];  b2s[t + 256] = b2[t + 256];
  g2s[t] = g2[t];  g2s[t + 256] = g2[t + 256];
  be2s[t] = be2[t]; be2s[t + 256] = be2[t + 256];
  bi1s[t] = bi1[t]; bi1s[t + 256] = bi1[t + 256];
  if (t < 64) b3s[t] = b3[t];
  if (t < 128) {   // stage shift_bits tile -> bf16 swizzled
    int row = t >> 3, g = t & 7;
    const float* src = shift_bits + (size_t)(b0 + row) * 64 + g * 8;
    uint4 pk;
    pk.x = (unsigned)f2bf(src[0]) | ((unsigned)f2bf(src[1]) << 16);
    pk.y = (unsigned)f2bf(src[2]) | ((unsigned)f2bf(src[3]) << 16);
    pk.z = (unsigned)f2bf(src[4]) | ((unsigned)f2bf(src[5]) << 16);
    pk.w = (unsigned)f2bf(src[6]) | ((unsigned)f2bf(src[7]) << 16);
    *(uint4*)((char*)sbt + ((row * 128 + g * 16) ^ ((row & 7) << 4))) = pk;
  }
  __syncthreads();

  // ----- GEMM1: x1[16][512] = sbt @ W1^T ; wave w owns cols [w*128, w*128+128) -----
  f32x4 acc[8];
#pragma unroll
  for (int nt = 0; nt < 8; ++nt) acc[nt] = (f32x4){0.f, 0.f, 0.f, 0.f};
#pragma unroll
  for (int ks = 0; ks < 2; ++ks) {
    bf16x8 af = *(const bf16x8*)((char*)sbt + ((l15 * 128 + ks * 64 + lg * 16) ^ ((l15 & 7) << 4)));
#pragma unroll
    for (int nt = 0; nt < 8; ++nt) {
      int c = w * 128 + nt * 16 + l15;
      bf16x8 bfr = *(const bf16x8*)(W1b + (size_t)c * 64 + ks * 32 + lg * 8);
      acc[nt] = __builtin_amdgcn_mfma_f32_16x16x32_bf16(af, bfr, acc[nt], 0, 0, 0);
    }
  }
  // ----- LN1 + relu -> hA -----
  {
    float s[4] = {0.f, 0.f, 0.f, 0.f}, q[4] = {0.f, 0.f, 0.f, 0.f};
#pragma unroll
    for (int nt = 0; nt < 8; ++nt) {
      int c = w * 128 + nt * 16 + l15;
      float bb = b1s[c];
#pragma unroll
      for (int r = 0; r < 4; ++r) {
        float x = acc[nt][r] + bb;
        acc[nt][r] = x;
        s[r] += x; q[r] += x * x;
      }
    }
#pragma unroll
    for (int m = 8; m >= 1; m >>= 1)
#pragma unroll
      for (int r = 0; r < 4; ++r) { s[r] += __shfl_xor(s[r], m); q[r] += __shfl_xor(q[r], m); }
    if (l15 == 0)
#pragma unroll
      for (int r = 0; r < 4; ++r) { red[w][4 * lg + r][0] = s[r]; red[w][4 * lg + r][1] = q[r]; }
    __syncthreads();
    float mean[4], rs[4];
#pragma unroll
    for (int r = 0; r < 4; ++r) {
      int p = 4 * lg + r;
      float S = red[0][p][0] + red[1][p][0] + red[2][p][0] + red[3][p][0];
      float Q = red[0][p][1] + red[1][p][1] + red[2][p][1] + red[3][p][1];
      mean[r] = S * (1.0f / 512.0f);
      float var = Q * (1.0f / 512.0f) - mean[r] * mean[r];
      rs[r] = rsqrtf(var + EPSV);
    }
#pragma unroll
    for (int nt = 0; nt < 8; ++nt) {
      int c = w * 128 + nt * 16 + l15;
      float gg = g1s[c], bb = be1s[c];
#pragma unroll
      for (int r = 0; r < 4; ++r) {
        int p = 4 * lg + r;
        float v = (acc[nt][r] - mean[r]) * rs[r] * gg + bb;
        v = v > 0.f ? v : 0.f;
        *(ushort_t*)((char*)hA + ((p * 1024 + c * 2) ^ ((p & 7) << 4))) = f2bf(v);
      }
    }
  }
  __syncthreads();

  // ----- GEMM2: x2[16][512] = hA @ W2^T, frag-order W2f, barrier-free -----
#pragma unroll
  for (int nt = 0; nt < 8; ++nt) acc[nt] = (f32x4){0.f, 0.f, 0.f, 0.f};
  {
    const bf16x8* w2base = (const bf16x8*)W2f + ((size_t)(w * 8) * 64 + l);
#pragma unroll 2
    for (int step = 0; step < 16; ++step) {
      bf16x8 af = *(const bf16x8*)((char*)hA + ((l15 * 1024 + step * 64 + lg * 16) ^ ((l15 & 7) << 4)));
#pragma unroll
      for (int nt = 0; nt < 8; ++nt) {
        bf16x8 bfr = w2base[((size_t)step * 32 + nt) * 64];
        acc[nt] = __builtin_amdgcn_mfma_f32_16x16x32_bf16(af, bfr, acc[nt], 0, 0, 0);
      }
    }
  }
  __syncthreads();   // hA reads done; h2 region (reg2) free for overwrite
  // ----- LN2 + relu -> h2 -----
  {
    float s[4] = {0.f, 0.f, 0.f, 0.f}, q[4] = {0.f, 0.f, 0.f, 0.f};
#pragma unroll
    for (int nt = 0; nt < 8; ++nt) {
      int c = w * 128 + nt * 16 + l15;
      float bb = b2s[c];
#pragma unroll
      for (int r = 0; r < 4; ++r) {
        float x = acc[nt][r] + bb;
        acc[nt][r] = x;
        s[r] += x; q[r] += x * x;
      }
    }
#pragma unroll
    for (int m = 8; m >= 1; m >>= 1)
#pragma unroll
      for (int r = 0; r < 4; ++r) { s[r] += __shfl_xor(s[r], m); q[r] += __shfl_xor(q[r], m); }
    if (l15 == 0)
#pragma unroll
      for (int r = 0; r < 4; ++r) { red[w][4 * lg + r][0] = s[r]; red[w][4 * lg + r][1] = q[r]; }
    __syncthreads();
    float mean[4], rs[4];
#pragma unroll
    for (int r = 0; r < 4; ++r) {
      int p = 4 * lg + r;
      float S = red[0][p][0] + red[1][p][0] + red[2][p][0] + red[3][p][0];
      float Q = red[0][p][1] + red[1][p][1] + red[2][p][1] + red[3][p][1];
      mean[r] = S * (1.0f / 512.0f);
      float var = Q * (1.0f / 512.0f) - mean[r] * mean[r];
      rs[r] = rsqrtf(var + EPSV);
    }
#pragma unroll
    for (int nt = 0; nt < 8; ++nt) {
      int c = w * 128 + nt * 16 + l15;
      float gg = g2s[c], bb = be2s[c];
#pragma unroll
      for (int r = 0; r < 4; ++r) {
        int p = 4 * lg + r;
        float v = (acc[nt][r] - mean[r]) * rs[r] * gg + bb;
        v = v > 0.f ? v : 0.f;
        *(ushort_t*)((char*)h2 + ((p * 1024 + c * 2) ^ ((p & 7) << 4))) = f2bf(v);
      }
    }
  }
  __syncthreads();

  // ----- GEMM3: logits[16][64] = h2 @ W3^T ; wave w owns cols [16w,16w+16) -----
  {
    f32x4 a3 = (f32x4){0.f, 0.f, 0.f, 0.f};
#pragma unroll
    for (int ks = 0; ks < 16; ++ks) {
      bf16x8 af = *(const bf16x8*)((char*)h2 + ((l15 * 1024 + ks * 64 + lg * 16) ^ ((l15 & 7) << 4)));
      bf16x8 bfr = *(const bf16x8*)(W3b + (size_t)(w * 16 + l15) * 512 + ks * 32 + lg * 8);
      a3 = __builtin_amdgcn_mfma_f32_16x16x32_bf16(af, bfr, a3, 0, 0, 0);
    }
    int c = w * 16 + l15;
    float bb = b3s[c];
#pragma unroll
    for (int r = 0; r < 4; ++r) lg32[4 * lg + r][c] = a3[r] + bb;
  }
  __syncthreads();

  // ----- softmax over 64 logits -> sb2 (bf16, swizzled) -----
  {
    int r = t >> 4, j = t & 15;
    float v[4];
    float m = -1e30f;
#pragma unroll
    for (int mq = 0; mq < 4; ++mq) { v[mq] = lg32[r][mq * 16 + j]; m = fmaxf(m, v[mq]); }
#pragma unroll
    for (int mk = 8; mk >= 1; mk >>= 1) m = fmaxf(m, __shfl_xor(m, mk));
    float ssum = 0.f;
#pragma unroll
    for (int mq = 0; mq < 4; ++mq) { v[mq] = expf(v[mq] - m); ssum += v[mq]; }
#pragma unroll
    for (int mk = 8; mk >= 1; mk >>= 1) ssum += __shfl_xor(ssum, mk);
    float inv = 1.f / ssum;
#pragma unroll
    for (int mq = 0; mq < 4; ++mq) {
      int c = mq * 16 + j;
      *(ushort_t*)((char*)sb2 + ((r * 128 + c * 2) ^ ((r & 7) << 4))) = f2bf(v[mq] * inv);
    }
  }
  __syncthreads();

  // ----- GEMM4: sp[16][512] = soft @ Wi1shift^T + bi1 -----
  {
    f32x4 a4[8];
#pragma unroll
    for (int nt = 0; nt < 8; ++nt) a4[nt] = (f32x4){0.f, 0.f, 0.f, 0.f};
#pragma unroll
    for (int ks = 0; ks < 2; ++ks) {
      bf16x8 af = *(const bf16x8*)((char*)sb2 + ((l15 * 128 + ks * 64 + lg * 16) ^ ((l15 & 7) << 4)));
#pragma unroll
      for (int nt = 0; nt < 8; ++nt) {
        int c = w * 128 + nt * 16 + l15;
        bf16x8 bfr = *(const bf16x8*)(Wi1sb + (size_t)c * 64 + ks * 32 + lg * 8);
        a4[nt] = __builtin_amdgcn_mfma_f32_16x16x32_bf16(af, bfr, a4[nt], 0, 0, 0);
      }
    }
#pragma unroll
    for (int nt = 0; nt < 8; ++nt) {
      int c = w * 128 + nt * 16 + l15;
      float bb = bi1s[c];
#pragma unroll
      for (int r = 0; r < 4; ++r)
        sp[(size_t)(b0 + 4 * lg + r) * 512 + c] = a4[nt][r] + bb;
    }
  }
}

// ---------------- big11: BM=32 half-row blocks, 4 waves, 4 blocks/CU ----------------
// Block = (batch row B = bid>>1, position half H = bid&1): rows H*32..H*32+31.
// 256 threads (4 waves). h1[32][512] LDS (&15 swizzle) = 32KB -> ~35KB total LDS
// -> 4 blocks/CU at 128 regs (the occupancy lever: 4 independent phase-chains).
// GEMM1 = mfma(Wi2frag, h1frag): wave w owns cols [128w,128w+128) (ct 4w..4w+3),
// acc[4] f32x16 (64 AGPR), ping-pong depth-2 B prefetch (4 contiguous 1KB bursts).
// h2 -> LDS uint2-packed (big6-verified layout). GEMM2 output-split (big10):
// wave = (p-tile w>>1, j-half w&1), full K, no reduction. Max-free softmax.
__global__ __launch_bounds__(256, 4) void big11_kernel(
    const float* __restrict__ a_bits, const float* __restrict__ sp,
    const ushort_t* __restrict__ posTb,
    const ushort_t* __restrict__ Wi2f32, const ushort_t* __restrict__ Wi3f,
    const float* __restrict__ bi2, const float* __restrict__ bi3,
    float* __restrict__ out) {
  __shared__ __align__(16) ushort_t h1s[32 * 512];   // 32KB; h1 -> h2 -> logits
  __shared__ float bi2s[512];
  __shared__ float ab[64];
  __shared__ float bi3s[64];

  int bid = blockIdx.x, t = threadIdx.x;
  int B = bid >> 1, H = bid & 1, prow0 = H * 32;
  int w = t >> 6, l = t & 63;
  int l31 = l & 31, hi = l >> 5;
  int lg = l >> 4, l15 = l & 15;

  bi2s[t] = bi2[t]; bi2s[t + 256] = bi2[t + 256];
  if (t < 64) { ab[t] = a_bits[B * 64 + t]; bi3s[t] = bi3[t]; }

  // ---- phase 0: h1[32][512] = relu(sp[B] + pos[prow0+p]) -> LDS bf16, swizzled ----
  {
    const float* sprow = sp + (size_t)B * 512 + l * 8;
    float4 s0 = *(const float4*)(sprow);
    float4 s1 = *(const float4*)(sprow + 4);
#pragma unroll
    for (int g = 0; g < 8; ++g) {
      int p = g * 4 + w;                    // wave w covers rows {w, 4+w, ..., 28+w}
      bf16x8 pr = *(const bf16x8*)(posTb + (size_t)(prow0 + p) * 512 + l * 8);
      float v0 = fmaxf(s0.x + bf2f(pr[0]), 0.f), v1 = fmaxf(s0.y + bf2f(pr[1]), 0.f);
      float v2 = fmaxf(s0.z + bf2f(pr[2]), 0.f), v3 = fmaxf(s0.w + bf2f(pr[3]), 0.f);
      float v4 = fmaxf(s1.x + bf2f(pr[4]), 0.f), v5 = fmaxf(s1.y + bf2f(pr[5]), 0.f);
      float v6 = fmaxf(s1.z + bf2f(pr[6]), 0.f), v7 = fmaxf(s1.w + bf2f(pr[7]), 0.f);
      uint4 pk;
      pk.x = pack2bf(v0, v1); pk.y = pack2bf(v2, v3);
      pk.z = pack2bf(v4, v5); pk.w = pack2bf(v6, v7);
      *(uint4*)((char*)h1s + ((p * 1024 + l * 16) ^ ((p & 15) << 4))) = pk;
    }
  }
  __syncthreads();

  // ---- GEMM1: mfma(Wi2, h1) ; 32x32x16, ping-pong depth-2, barrier-free ----
  f32x16 acc[4];   // acc[ct]: reg<->c (c = 128w + 32ct + ...), lane<->p
#pragma unroll
  for (int ct = 0; ct < 4; ++ct)
#pragma unroll
    for (int r = 0; r < 16; ++r) acc[ct][r] = 0.f;

  {
    // frag (ks, ct4w+n) at bf16x8 index (ks*16 + 4w + n)*64 + l
    const bf16x8* bbase = (const bf16x8*)Wi2f32 + ((size_t)(4 * w) * 64 + l);
    bf16x8 wfA[4], wfB[4];
#pragma unroll
    for (int n = 0; n < 4; ++n) wfA[n] = bbase[n * 64];            // ks=0
    for (int ks = 0; ks < 32; ks += 2) {
#pragma unroll
      for (int n = 0; n < 4; ++n) wfB[n] = bbase[(size_t)(ks + 1) * 1024 + n * 64];
      {
        bf16x8 a0 = *(const bf16x8*)((char*)h1s + ((l31 * 1024 + ks * 32 + hi * 16) ^ ((l31 & 15) << 4)));
        __builtin_amdgcn_s_setprio(1);
        acc[0] = __builtin_amdgcn_mfma_f32_32x32x16_bf16(wfA[0], a0, acc[0], 0, 0, 0);
        acc[1] = __builtin_amdgcn_mfma_f32_32x32x16_bf16(wfA[1], a0, acc[1], 0, 0, 0);
        acc[2] = __builtin_amdgcn_mfma_f32_32x32x16_bf16(wfA[2], a0, acc[2], 0, 0, 0);
        acc[3] = __builtin_amdgcn_mfma_f32_32x32x16_bf16(wfA[3], a0, acc[3], 0, 0, 0);
        __builtin_amdgcn_s_setprio(0);
      }
      if (ks < 30) {
#pragma unroll
        for (int n = 0; n < 4; ++n) wfA[n] = bbase[(size_t)(ks + 2) * 1024 + n * 64];
      }
      {
        bf16x8 a1 = *(const bf16x8*)((char*)h1s + ((l31 * 1024 + (ks + 1) * 32 + hi * 16) ^ ((l31 & 15) << 4)));
        __builtin_amdgcn_s_setprio(1);
        acc[0] = __builtin_amdgcn_mfma_f32_32x32x16_bf16(wfB[0], a1, acc[0], 0, 0, 0);
        acc[1] = __builtin_amdgcn_mfma_f32_32x32x16_bf16(wfB[1], a1, acc[1], 0, 0, 0);
        acc[2] = __builtin_amdgcn_mfma_f32_32x32x16_bf16(wfB[2], a1, acc[2], 0, 0, 0);
        acc[3] = __builtin_amdgcn_mfma_f32_32x32x16_bf16(wfB[3], a1, acc[3], 0, 0, 0);
        __builtin_amdgcn_s_setprio(0);
      }
    }
  }
  __syncthreads();   // all waves done reading h1 -> safe to overwrite with h2

  // ---- h2 = relu(acc + bi2) -> h1s region, packed uint2 writes (big6-verified) ----
  // p = l31 ; c = w*128 + ct*32 + (r&3) + 8*(r>>2) + 4*hi
#pragma unroll
  for (int ct = 0; ct < 4; ++ct) {
    int p = l31;
#pragma unroll
    for (int rq = 0; rq < 4; ++rq) {
      int c0 = w * 128 + ct * 32 + 8 * rq + 4 * hi;
      float4 bi4 = *(const float4*)(bi2s + c0);
      float v0 = fmaxf(acc[ct][4 * rq + 0] + bi4.x, 0.f);
      float v1 = fmaxf(acc[ct][4 * rq + 1] + bi4.y, 0.f);
      float v2 = fmaxf(acc[ct][4 * rq + 2] + bi4.z, 0.f);
      float v3 = fmaxf(acc[ct][4 * rq + 3] + bi4.w, 0.f);
      uint2 pk;
      pk.x = pack2bf(v0, v1);
      pk.y = pack2bf(v2, v3);
      *(uint2*)((char*)h1s + ((p * 1024 + c0 * 2) ^ ((p & 15) << 4))) = pk;
    }
  }
  __syncthreads();

  // ---- GEMM2 (4 waves, output-split, full K, NO reduction) ----
  // wave w: p-tile pt = w>>1 (16 rows), j-half jh = w&1 (2 j-tiles of 16)
  f32x4 lacc[2];
  lacc[0] = (f32x4){0.f, 0.f, 0.f, 0.f};
  lacc[1] = (f32x4){0.f, 0.f, 0.f, 0.f};
  {
    int pt = w >> 1, jh = w & 1;
    int p2 = 16 * pt + l15;
    const bf16x8* b3base = (const bf16x8*)Wi3f + l;
#pragma unroll 4
    for (int ks2 = 0; ks2 < 16; ++ks2) {
      bf16x8 a2 = *(const bf16x8*)((char*)h1s + ((p2 * 1024 + ks2 * 64 + lg * 16) ^ ((p2 & 15) << 4)));
      bf16x8 g0 = b3base[(ks2 * 4 + 2 * jh + 0) * 64];
      bf16x8 g1 = b3base[(ks2 * 4 + 2 * jh + 1) * 64];
      __builtin_amdgcn_s_setprio(1);
      lacc[0] = __builtin_amdgcn_mfma_f32_16x16x32_bf16(a2, g0, lacc[0], 0, 0, 0);
      lacc[1] = __builtin_amdgcn_mfma_f32_16x16x32_bf16(a2, g1, lacc[1], 0, 0, 0);
      __builtin_amdgcn_s_setprio(0);
    }
  }
  __syncthreads();   // all waves done reading h2 -> safe to overwrite with logits

  // ---- logits -> LDS f32 [32][pitch 68] (2-way banks), written ONCE ----
  {
    float* Lg = (float*)h1s;
    int pt = w >> 1, jh = w & 1;
#pragma unroll
    for (int q = 0; q < 2; ++q) {
      int j = (2 * jh + q) * 16 + l15;
#pragma unroll
      for (int r = 0; r < 4; ++r) {
        int p = pt * 16 + 4 * lg + r;
        Lg[p * 68 + j] = lacc[q][r];
      }
    }
  }
  __syncthreads();

  // ---- max-free softmax + gather (verified R8: logits tiny, exp safe) ----
  {
    const float* Lg = (const float*)h1s;
    int p = t >> 3, jo = t & 7;
    float s = 0.f, g = 0.f;
#pragma unroll
    for (int m = 0; m < 8; ++m) {
      int c = jo * 8 + m;
      float e = __expf(Lg[p * 68 + c] + bi3s[c]);
      s += e; g += e * ab[c];
    }
#pragma unroll
    for (int mm = 4; mm >= 1; mm >>= 1) { s += __shfl_xor(s, mm); g += __shfl_xor(g, mm); }
    if (jo == 0) out[B * 64 + prow0 + p] = g / s;
  }
}

extern "C" void kernel_launch(void* const* d_in, const int* in_sizes, int n_in,
                              void* d_out, int out_size, void* d_ws, size_t ws_size,
                              hipStream_t stream) {
  const float* a_bits     = (const float*)d_in[0];
  const float* shift_bits = (const float*)d_in[1];
  const float* W1  = (const float*)d_in[2];
  const float* b1  = (const float*)d_in[3];
  const float* g1  = (const float*)d_in[4];
  const float* be1 = (const float*)d_in[5];
  const float* W2  = (const float*)d_in[6];
  const float* b2  = (const float*)d_in[7];
  const float* g2  = (const float*)d_in[8];
  const float* be2 = (const float*)d_in[9];
  const float* W3  = (const float*)d_in[10];
  const float* b3  = (const float*)d_in[11];
  const float* Wi1 = (const float*)d_in[12];
  const float* bi1 = (const float*)d_in[13];
  const float* Wi2 = (const float*)d_in[14];
  const float* bi2 = (const float*)d_in[15];
  const float* Wi3 = (const float*)d_in[16];
  const float* bi3 = (const float*)d_in[17];
  float* out = (float*)d_out;

  // ws layout: sp fp32 [B][512] (8MB) | W2f (512KB) | W1b (64KB) | W3b (64KB)
  //            | Wi1sb (64KB) | Wi1posTb bf16 (64KB) | Wi2f32 (512KB) | Wi3f (64KB)
  float* sp = (float*)d_ws;
  ushort_t* W2f = (ushort_t*)((char*)d_ws + (size_t)B_N * HID * 4);
  ushort_t* W1b = W2f + 512 * 512;
  ushort_t* W3b = W1b + 512 * 64;
  ushort_t* Wi1sb = W3b + 64 * 512;
  ushort_t* Wi1posTb = Wi1sb + 512 * 64;
  ushort_t* Wi2f32 = Wi1posTb + 64 * 512;
  ushort_t* Wi3f = Wi2f32 + 512 * 512;

  prep_kernel<<<1024, 256, 0, stream>>>(Wi2, Wi3, Wi1, W1, W2, W3,
                                        Wi1posTb, W1b, W2f, W3b, Wi1sb, Wi2f32, Wi3f);
  shift2_kernel<<<B_N / BT, 256, 0, stream>>>(shift_bits, W1b, b1, g1, be1,
                                              W2f, b2, g2, be2, W3b, b3, Wi1sb, bi1, sp);
  big11_kernel<<<B_N * 2, 256, 0, stream>>>(a_bits, sp, Wi1posTb, Wi2f32, Wi3f, bi2, bi3, out);
}

// Round 13
// 201.226 us; speedup vs baseline: 1.1634x; 1.1634x over previous
//
#include <hip/hip_runtime.h>
#include <hip/hip_bf16.h>
#include <math.h>

// Problem constants
#define B_N 4096
#define BITSN 64
#define HID 512
#define EPSV 1e-5f
#define BT 16   // batch rows per shift2 block

typedef unsigned short ushort_t;
typedef __attribute__((ext_vector_type(8))) short bf16x8;
typedef __attribute__((ext_vector_type(4))) float f32x4;
typedef __attribute__((ext_vector_type(16))) float f32x16;

__device__ __forceinline__ ushort_t f2bf(float f) {
  unsigned u = __float_as_uint(f);
  u += 0x7FFF + ((u >> 16) & 1);   // round-to-nearest-even
  return (ushort_t)(u >> 16);
}

__device__ __forceinline__ unsigned pack2bf(float lo, float hi) {
  union { __hip_bfloat162 h; unsigned u; } cv;
  cv.h = __float22bfloat162_rn(make_float2(lo, hi));  // v_cvt_pk_bf16_f32
  return cv.u;
}

__device__ __forceinline__ float bf2f(short v) {
  return __uint_as_float(((unsigned)(unsigned short)v) << 16);
}

// ---------------- prep: bf16 copies, transposes, FRAGMENT-ORDER weights ----
// Wi2f32: 32x32x16 frag order (big GEMM1 B). Frag (ks 0..31, ct 0..15) lane l:
//   Wi2[ct*32 + (l&31)][ks*16 + (l>>5)*8 + j].
// W2f: 16x16x32 frag order (shift2 GEMM2 B, verified R5/R10).
// Wi3g: big GEMM2 B in the (e,hi)->c permutation the in-register h2 pack
//   produces (verified R8/R10).
// Wi1posTb: bf16 pos_part transpose [64][512].
__global__ __launch_bounds__(256) void prep_kernel(
    const float* __restrict__ Wi2, const float* __restrict__ Wi3,
    const float* __restrict__ Wi1, const float* __restrict__ W1,
    const float* __restrict__ W2, const float* __restrict__ W3,
    ushort_t* __restrict__ Wi1posTb, ushort_t* __restrict__ W1b,
    ushort_t* __restrict__ W2f, ushort_t* __restrict__ W3b,
    ushort_t* __restrict__ Wi1sb, ushort_t* __restrict__ Wi2f32,
    ushort_t* __restrict__ Wi3g) {
  int idx = blockIdx.x * 256 + threadIdx.x;
  if (idx < 512 * 512) {
    // W2f (16x16x32 frag order) for shift2 GEMM2
    {
      int j = idx & 7, lane = (idx >> 3) & 63;
      int ct = (idx >> 9) & 31, ks = idx >> 14;
      int c = ct * 16 + (lane & 15);
      int k = ks * 32 + (lane >> 4) * 8 + j;
      W2f[idx] = f2bf(W2[c * 512 + k]);
    }
    // Wi2f32 (32x32x16 frag order) for big GEMM1
    {
      int j = idx & 7, lane = (idx >> 3) & 63;
      int ct = (idx >> 9) & 15, ks = idx >> 13;
      int c = ct * 32 + (lane & 31);
      int k = ks * 16 + (lane >> 5) * 8 + j;
      Wi2f32[idx] = f2bf(Wi2[c * 512 + k]);
    }
  }
  if (idx < 64 * 512) {
    W3b[idx] = f2bf(W3[idx]);
    int p = idx >> 9, i = idx & 511;
    Wi1posTb[idx] = f2bf(Wi1[i * 128 + p]);   // pos_part[p][i] = Wi1[i][p], bf16
    // Wi3g dst-linear scatter (verified R8)
    int e = idx & 7, lane = (idx >> 3) & 63;
    int jt = (idx >> 9) & 1, h = (idx >> 10) & 1;
    int mc = (idx >> 11) & 1, w = idx >> 12;
    int jr = jt * 32 + (lane & 31);
    int c = w * 64 + mc * 32 + 16 * h + 4 * (lane >> 5) + (e & 3) + 8 * (e >> 2);
    Wi3g[idx] = f2bf(Wi3[jr * 512 + c]);
  }
  if (idx < 512 * 64) {
    W1b[idx] = f2bf(W1[idx]);                       // [512][64]
    int j = idx >> 6, k = idx & 63;
    Wi1sb[idx] = f2bf(Wi1[j * 128 + 64 + k]);       // shift cols of Wi1: [512][64]
  }
}

// ---------------- shift decoder, MFMA-batched: 16 rows/block ----------------
__global__ __launch_bounds__(256) void shift2_kernel(
    const float* __restrict__ shift_bits,
    const ushort_t* __restrict__ W1b, const float* __restrict__ b1,
    const float* __restrict__ g1, const float* __restrict__ be1,
    const ushort_t* __restrict__ W2f, const float* __restrict__ b2,
    const float* __restrict__ g2, const float* __restrict__ be2,
    const ushort_t* __restrict__ W3b, const float* __restrict__ b3,
    const ushort_t* __restrict__ Wi1sb, const float* __restrict__ bi1,
    float* __restrict__ sp) {
  __shared__ __align__(16) ushort_t hA[BT * 512];     // 16KB: h1 (post LN1+relu)
  __shared__ __align__(16) char reg2[32 * 1024];      // phase union
  __shared__ float b1s[512], g1s[512], be1s[512];
  __shared__ float b2s[512], g2s[512], be2s[512], bi1s[512];
  __shared__ float red[4][BT][2];
  __shared__ float b3s[64];

  ushort_t* sbt = (ushort_t*)reg2;                    // phase 1: shift_bits tile [16][64]
  ushort_t* h2  = (ushort_t*)reg2;                    // phase 3: h2 [16][512]
  float (*lg32)[68] = (float(*)[68])(reg2 + 16 * 1024);
  ushort_t* sb2 = (ushort_t*)(reg2 + 16 * 1024 + 16 * 68 * 4);  // soft [16][64]

  int b0 = blockIdx.x * BT;
  int t = threadIdx.x, w = t >> 6, l = t & 63, lg = l >> 4, l15 = l & 15;

  b1s[t] = b1[t];  b1s[t + 256] = b1[t + 256];
  g1s[t] = g1[t];  g1s[t + 256] = g1[t + 256];
  be1s[t] = be1[t]; be1s[t + 256] = be1[t + 256];
  b2s[t] = b2[t];  b2s[t + 256] = b2[t + 256];
  g2s[t] = g2[t];  g2s[t + 256] = g2[t + 256];
  be2s[t] = be2[t]; be2s[t + 256] = be2[t + 256];
  bi1s[t] = bi1[t]; bi1s[t + 256] = bi1[t + 256];
  if (t < 64) b3s[t] = b3[t];
  if (t < 128) {   // stage shift_bits tile -> bf16 swizzled
    int row = t >> 3, g = t & 7;
    const float* src = shift_bits + (size_t)(b0 + row) * 64 + g * 8;
    uint4 pk;
    pk.x = (unsigned)f2bf(src[0]) | ((unsigned)f2bf(src[1]) << 16);
    pk.y = (unsigned)f2bf(src[2]) | ((unsigned)f2bf(src[3]) << 16);
    pk.z = (unsigned)f2bf(src[4]) | ((unsigned)f2bf(src[5]) << 16);
    pk.w = (unsigned)f2bf(src[6]) | ((unsigned)f2bf(src[7]) << 16);
    *(uint4*)((char*)sbt + ((row * 128 + g * 16) ^ ((row & 7) << 4))) = pk;
  }
  __syncthreads();

  // ----- GEMM1: x1[16][512] = sbt @ W1^T ; wave w owns cols [w*128, w*128+128) -----
  f32x4 acc[8];
#pragma unroll
  for (int nt = 0; nt < 8; ++nt) acc[nt] = (f32x4){0.f, 0.f, 0.f, 0.f};
#pragma unroll
  for (int ks = 0; ks < 2; ++ks) {
    bf16x8 af = *(const bf16x8*)((char*)sbt + ((l15 * 128 + ks * 64 + lg * 16) ^ ((l15 & 7) << 4)));
#pragma unroll
    for (int nt = 0; nt < 8; ++nt) {
      int c = w * 128 + nt * 16 + l15;
      bf16x8 bfr = *(const bf16x8*)(W1b + (size_t)c * 64 + ks * 32 + lg * 8);
      acc[nt] = __builtin_amdgcn_mfma_f32_16x16x32_bf16(af, bfr, acc[nt], 0, 0, 0);
    }
  }
  // ----- LN1 + relu -> hA -----
  {
    float s[4] = {0.f, 0.f, 0.f, 0.f}, q[4] = {0.f, 0.f, 0.f, 0.f};
#pragma unroll
    for (int nt = 0; nt < 8; ++nt) {
      int c = w * 128 + nt * 16 + l15;
      float bb = b1s[c];
#pragma unroll
      for (int r = 0; r < 4; ++r) {
        float x = acc[nt][r] + bb;
        acc[nt][r] = x;
        s[r] += x; q[r] += x * x;
      }
    }
#pragma unroll
    for (int m = 8; m >= 1; m >>= 1)
#pragma unroll
      for (int r = 0; r < 4; ++r) { s[r] += __shfl_xor(s[r], m); q[r] += __shfl_xor(q[r], m); }
    if (l15 == 0)
#pragma unroll
      for (int r = 0; r < 4; ++r) { red[w][4 * lg + r][0] = s[r]; red[w][4 * lg + r][1] = q[r]; }
    __syncthreads();
    float mean[4], rs[4];
#pragma unroll
    for (int r = 0; r < 4; ++r) {
      int p = 4 * lg + r;
      float S = red[0][p][0] + red[1][p][0] + red[2][p][0] + red[3][p][0];
      float Q = red[0][p][1] + red[1][p][1] + red[2][p][1] + red[3][p][1];
      mean[r] = S * (1.0f / 512.0f);
      float var = Q * (1.0f / 512.0f) - mean[r] * mean[r];
      rs[r] = rsqrtf(var + EPSV);
    }
#pragma unroll
    for (int nt = 0; nt < 8; ++nt) {
      int c = w * 128 + nt * 16 + l15;
      float gg = g1s[c], bb = be1s[c];
#pragma unroll
      for (int r = 0; r < 4; ++r) {
        int p = 4 * lg + r;
        float v = (acc[nt][r] - mean[r]) * rs[r] * gg + bb;
        v = v > 0.f ? v : 0.f;
        *(ushort_t*)((char*)hA + ((p * 1024 + c * 2) ^ ((p & 7) << 4))) = f2bf(v);
      }
    }
  }
  __syncthreads();

  // ----- GEMM2: x2[16][512] = hA @ W2^T, frag-order W2f, barrier-free -----
#pragma unroll
  for (int nt = 0; nt < 8; ++nt) acc[nt] = (f32x4){0.f, 0.f, 0.f, 0.f};
  {
    const bf16x8* w2base = (const bf16x8*)W2f + ((size_t)(w * 8) * 64 + l);
#pragma unroll 2
    for (int step = 0; step < 16; ++step) {
      bf16x8 af = *(const bf16x8*)((char*)hA + ((l15 * 1024 + step * 64 + lg * 16) ^ ((l15 & 7) << 4)));
#pragma unroll
      for (int nt = 0; nt < 8; ++nt) {
        bf16x8 bfr = w2base[((size_t)step * 32 + nt) * 64];
        acc[nt] = __builtin_amdgcn_mfma_f32_16x16x32_bf16(af, bfr, acc[nt], 0, 0, 0);
      }
    }
  }
  __syncthreads();   // hA reads done; h2 region (reg2) free for overwrite
  // ----- LN2 + relu -> h2 -----
  {
    float s[4] = {0.f, 0.f, 0.f, 0.f}, q[4] = {0.f, 0.f, 0.f, 0.f};
#pragma unroll
    for (int nt = 0; nt < 8; ++nt) {
      int c = w * 128 + nt * 16 + l15;
      float bb = b2s[c];
#pragma unroll
      for (int r = 0; r < 4; ++r) {
        float x = acc[nt][r] + bb;
        acc[nt][r] = x;
        s[r] += x; q[r] += x * x;
      }
    }
#pragma unroll
    for (int m = 8; m >= 1; m >>= 1)
#pragma unroll
      for (int r = 0; r < 4; ++r) { s[r] += __shfl_xor(s[r], m); q[r] += __shfl_xor(q[r], m); }
    if (l15 == 0)
#pragma unroll
      for (int r = 0; r < 4; ++r) { red[w][4 * lg + r][0] = s[r]; red[w][4 * lg + r][1] = q[r]; }
    __syncthreads();
    float mean[4], rs[4];
#pragma unroll
    for (int r = 0; r < 4; ++r) {
      int p = 4 * lg + r;
      float S = red[0][p][0] + red[1][p][0] + red[2][p][0] + red[3][p][0];
      float Q = red[0][p][1] + red[1][p][1] + red[2][p][1] + red[3][p][1];
      mean[r] = S * (1.0f / 512.0f);
      float var = Q * (1.0f / 512.0f) - mean[r] * mean[r];
      rs[r] = rsqrtf(var + EPSV);
    }
#pragma unroll
    for (int nt = 0; nt < 8; ++nt) {
      int c = w * 128 + nt * 16 + l15;
      float gg = g2s[c], bb = be2s[c];
#pragma unroll
      for (int r = 0; r < 4; ++r) {
        int p = 4 * lg + r;
        float v = (acc[nt][r] - mean[r]) * rs[r] * gg + bb;
        v = v > 0.f ? v : 0.f;
        *(ushort_t*)((char*)h2 + ((p * 1024 + c * 2) ^ ((p & 7) << 4))) = f2bf(v);
      }
    }
  }
  __syncthreads();

  // ----- GEMM3: logits[16][64] = h2 @ W3^T ; wave w owns cols [16w,16w+16) -----
  {
    f32x4 a3 = (f32x4){0.f, 0.f, 0.f, 0.f};
#pragma unroll
    for (int ks = 0; ks < 16; ++ks) {
      bf16x8 af = *(const bf16x8*)((char*)h2 + ((l15 * 1024 + ks * 64 + lg * 16) ^ ((l15 & 7) << 4)));
      bf16x8 bfr = *(const bf16x8*)(W3b + (size_t)(w * 16 + l15) * 512 + ks * 32 + lg * 8);
      a3 = __builtin_amdgcn_mfma_f32_16x16x32_bf16(af, bfr, a3, 0, 0, 0);
    }
    int c = w * 16 + l15;
    float bb = b3s[c];
#pragma unroll
    for (int r = 0; r < 4; ++r) lg32[4 * lg + r][c] = a3[r] + bb;
  }
  __syncthreads();

  // ----- softmax over 64 logits -> sb2 (bf16, swizzled) -----
  {
    int r = t >> 4, j = t & 15;
    float v[4];
    float m = -1e30f;
#pragma unroll
    for (int mq = 0; mq < 4; ++mq) { v[mq] = lg32[r][mq * 16 + j]; m = fmaxf(m, v[mq]); }
#pragma unroll
    for (int mk = 8; mk >= 1; mk >>= 1) m = fmaxf(m, __shfl_xor(m, mk));
    float ssum = 0.f;
#pragma unroll
    for (int mq = 0; mq < 4; ++mq) { v[mq] = expf(v[mq] - m); ssum += v[mq]; }
#pragma unroll
    for (int mk = 8; mk >= 1; mk >>= 1) ssum += __shfl_xor(ssum, mk);
    float inv = 1.f / ssum;
#pragma unroll
    for (int mq = 0; mq < 4; ++mq) {
      int c = mq * 16 + j;
      *(ushort_t*)((char*)sb2 + ((r * 128 + c * 2) ^ ((r & 7) << 4))) = f2bf(v[mq] * inv);
    }
  }
  __syncthreads();

  // ----- GEMM4: sp[16][512] = soft @ Wi1shift^T + bi1 -----
  {
    f32x4 a4[8];
#pragma unroll
    for (int nt = 0; nt < 8; ++nt) a4[nt] = (f32x4){0.f, 0.f, 0.f, 0.f};
#pragma unroll
    for (int ks = 0; ks < 2; ++ks) {
      bf16x8 af = *(const bf16x8*)((char*)sb2 + ((l15 * 128 + ks * 64 + lg * 16) ^ ((l15 & 7) << 4)));
#pragma unroll
      for (int nt = 0; nt < 8; ++nt) {
        int c = w * 128 + nt * 16 + l15;
        bf16x8 bfr = *(const bf16x8*)(Wi1sb + (size_t)c * 64 + ks * 32 + lg * 8);
        a4[nt] = __builtin_amdgcn_mfma_f32_16x16x32_bf16(af, bfr, a4[nt], 0, 0, 0);
      }
    }
#pragma unroll
    for (int nt = 0; nt < 8; ++nt) {
      int c = w * 128 + nt * 16 + l15;
      float bb = bi1s[c];
#pragma unroll
      for (int r = 0; r < 4; ++r)
        sp[(size_t)(b0 + 4 * lg + r) * 512 + c] = a4[nt][r] + bb;
    }
  }
}

// ---------------- big12: big9 + pair-packed partial reduction (cvt_pk, uint stores) ----
// BM=64 (1 batch row), BN=512, 8 waves. h1[64][512] LDS (&15 swizzle), bf16 posT.
// GEMM1 = mfma(Wi2frag, h1frag), depth-4 B prefetch, setprio. h2 in regs ->
// pack (verified R8) -> GEMM2 in-reg, 8-wave K-split (verified R9/R10).
// Partial reduction: wave w stores its 64x64 bf16 partial as PAIRS:
// uint at Pu_w[p*34 + q] = (partial[p][q], partial[p][q+32]) via ONE cvt_pk.
// Pitch 34 uints: store bank = (2p+q)%32, q=l31 distinct per lane -> conflict-free;
// softmax reads 4 uints/region at q=jo+8k -> <=4 lanes/bank (~free).
__global__ __launch_bounds__(512, 4) void big12_kernel(
    const float* __restrict__ a_bits, const float* __restrict__ sp,
    const ushort_t* __restrict__ posTb,
    const ushort_t* __restrict__ Wi2f32, const ushort_t* __restrict__ Wi3g,
    const float* __restrict__ bi2, const float* __restrict__ bi3,
    float* __restrict__ out) {
  // 8 regions x 64 rows x 34 uints = 69632 B; h1 phase uses first 65536 B.
  __shared__ __align__(16) ushort_t h1s[34816];
  __shared__ float bi2s[512];
  __shared__ float ab[64];
  __shared__ float bi3s[64];

  int b = blockIdx.x, t = threadIdx.x;
  int w = t >> 6, l = t & 63;
  int l31 = l & 31, hi = l >> 5;

  bi2s[t] = bi2[t];
  if (t < 64) { ab[t] = a_bits[b * 64 + t]; bi3s[t] = bi3[t]; }

  // ---- phase 0: h1[64][512] = relu(sp[b] + pos) -> LDS bf16, swizzled, ONCE ----
  {
    const float* sprow = sp + (size_t)b * 512 + l * 8;
    float4 s0 = *(const float4*)(sprow);
    float4 s1 = *(const float4*)(sprow + 4);
#pragma unroll
    for (int g = 0; g < 8; ++g) {
      int p = g * 8 + w;                    // wave w covers rows {w, 8+w, ..., 56+w}
      bf16x8 pr = *(const bf16x8*)(posTb + (size_t)p * 512 + l * 8);
      float v0 = fmaxf(s0.x + bf2f(pr[0]), 0.f), v1 = fmaxf(s0.y + bf2f(pr[1]), 0.f);
      float v2 = fmaxf(s0.z + bf2f(pr[2]), 0.f), v3 = fmaxf(s0.w + bf2f(pr[3]), 0.f);
      float v4 = fmaxf(s1.x + bf2f(pr[4]), 0.f), v5 = fmaxf(s1.y + bf2f(pr[5]), 0.f);
      float v6 = fmaxf(s1.z + bf2f(pr[6]), 0.f), v7 = fmaxf(s1.w + bf2f(pr[7]), 0.f);
      uint4 pk;
      pk.x = pack2bf(v0, v1); pk.y = pack2bf(v2, v3);
      pk.z = pack2bf(v4, v5); pk.w = pack2bf(v6, v7);
      *(uint4*)((char*)h1s + ((p * 1024 + l * 16) ^ ((p & 15) << 4))) = pk;
    }
  }
  __syncthreads();

  // ---- GEMM1: mfma(Wi2, h1) ; 32x32x16, depth-4 B prefetch, barrier-free ----
  f32x16 acc[2][2];   // acc[mc][np]: reg<->c (c-tile mc), lane<->p (p-tile np)
#pragma unroll
  for (int mc = 0; mc < 2; ++mc)
#pragma unroll
    for (int np = 0; np < 2; ++np)
#pragma unroll
      for (int r = 0; r < 16; ++r) acc[mc][np][r] = 0.f;

  {
    const bf16x8* bbase = (const bf16x8*)Wi2f32 + ((size_t)(2 * w) * 64 + l);
    bf16x8 wf[4][2];
#pragma unroll
    for (int d = 0; d < 4; ++d) {
      wf[d][0] = bbase[(size_t)d * 1024];
      wf[d][1] = bbase[(size_t)d * 1024 + 64];
    }
    for (int kb = 0; kb < 8; ++kb) {
#pragma unroll
      for (int d = 0; d < 4; ++d) {
        int ks = kb * 4 + d;
        bf16x8 w0 = wf[d][0], w1 = wf[d][1];
        if (kb < 7) {
          wf[d][0] = bbase[(size_t)(ks + 4) * 1024];
          wf[d][1] = bbase[(size_t)(ks + 4) * 1024 + 64];
        }
        int row0 = l31, row1 = 32 + l31;
        bf16x8 h0 = *(const bf16x8*)((char*)h1s + ((row0 * 1024 + ks * 32 + hi * 16) ^ ((row0 & 15) << 4)));
        bf16x8 h1v = *(const bf16x8*)((char*)h1s + ((row1 * 1024 + ks * 32 + hi * 16) ^ ((row1 & 15) << 4)));
        __builtin_amdgcn_s_setprio(1);
        acc[0][0] = __builtin_amdgcn_mfma_f32_32x32x16_bf16(w0, h0, acc[0][0], 0, 0, 0);
        acc[0][1] = __builtin_amdgcn_mfma_f32_32x32x16_bf16(w0, h1v, acc[0][1], 0, 0, 0);
        acc[1][0] = __builtin_amdgcn_mfma_f32_32x32x16_bf16(w1, h0, acc[1][0], 0, 0, 0);
        acc[1][1] = __builtin_amdgcn_mfma_f32_32x32x16_bf16(w1, h1v, acc[1][1], 0, 0, 0);
        __builtin_amdgcn_s_setprio(0);
      }
    }
  }

  // ---- h2 = relu(acc + bi2), pack to bf16 A-frags in regs (layout verified R8) ----
  bf16x8 pkf[2][2][2];   // [np][mc][h]
#pragma unroll
  for (int mc = 0; mc < 2; ++mc) {
    float bia[16];
#pragma unroll
    for (int rq = 0; rq < 4; ++rq) {
      int c0 = w * 64 + mc * 32 + 8 * rq + 4 * hi;
      float4 bi4 = *(const float4*)(bi2s + c0);
      bia[4 * rq + 0] = bi4.x; bia[4 * rq + 1] = bi4.y;
      bia[4 * rq + 2] = bi4.z; bia[4 * rq + 3] = bi4.w;
    }
#pragma unroll
    for (int np = 0; np < 2; ++np) {
      float hv[16];
#pragma unroll
      for (int r = 0; r < 16; ++r) hv[r] = fmaxf(acc[mc][np][r] + bia[r], 0.f);
#pragma unroll
      for (int h = 0; h < 2; ++h) {
        unsigned d0 = pack2bf(hv[8 * h + 0], hv[8 * h + 1]);
        unsigned d1 = pack2bf(hv[8 * h + 2], hv[8 * h + 3]);
        unsigned d2 = pack2bf(hv[8 * h + 4], hv[8 * h + 5]);
        unsigned d3 = pack2bf(hv[8 * h + 6], hv[8 * h + 7]);
        union { unsigned u[4]; bf16x8 v; } cv;
        cv.u[0] = d0; cv.u[1] = d1; cv.u[2] = d2; cv.u[3] = d3;
        pkf[np][mc][h] = cv.v;
      }
    }
  }
  __syncthreads();   // all waves done reading h1s -> safe to reuse as partials

  // ---- GEMM2: partial logits over this wave's 64-c chunk, fully in-reg ----
  f32x16 l00, l01, l10, l11;
#pragma unroll
  for (int r = 0; r < 16; ++r) { l00[r] = 0.f; l01[r] = 0.f; l10[r] = 0.f; l11[r] = 0.f; }
  {
    const bf16x8* gbase = (const bf16x8*)Wi3g + ((size_t)w * 8 * 64 + l);
#pragma unroll
    for (int mc = 0; mc < 2; ++mc) {
#pragma unroll
      for (int h = 0; h < 2; ++h) {
        bf16x8 g0 = gbase[((mc * 2 + h) * 2 + 0) * 64];
        bf16x8 g1 = gbase[((mc * 2 + h) * 2 + 1) * 64];
        __builtin_amdgcn_s_setprio(1);
        l00 = __builtin_amdgcn_mfma_f32_32x32x16_bf16(pkf[0][mc][h], g0, l00, 0, 0, 0);
        l01 = __builtin_amdgcn_mfma_f32_32x32x16_bf16(pkf[0][mc][h], g1, l01, 0, 0, 0);
        l10 = __builtin_amdgcn_mfma_f32_32x32x16_bf16(pkf[1][mc][h], g0, l10, 0, 0, 0);
        l11 = __builtin_amdgcn_mfma_f32_32x32x16_bf16(pkf[1][mc][h], g1, l11, 0, 0, 0);
        __builtin_amdgcn_s_setprio(0);
      }
    }
  }

  // ---- pair-packed partial store: Pu_w[p*34 + q] = (P[p][q], P[p][q+32]) ----
  // D: lane<->j (jt*32+l31 -> l00/l10 j=l31, l01/l11 j=32+l31), reg<->p.
  // One cvt_pk per pair; pitch-34 banks = (2p+q)%32, q=l31 -> conflict-free.
  {
    unsigned* Pu = (unsigned*)h1s + (size_t)w * 2176;   // 64*34 uints per wave
#pragma unroll
    for (int r = 0; r < 16; ++r) {
      int p0 = (r & 3) + 8 * (r >> 2) + 4 * hi;
      int p1 = p0 + 32;
      Pu[p0 * 34 + l31] = pack2bf(l00[r], l01[r]);
      Pu[p1 * 34 + l31] = pack2bf(l10[r], l11[r]);
    }
  }
  __syncthreads();

  // ---- max-free softmax + gather: thread (p=t>>3, jo=t&7) sums 8 regions ----
  // Column set per thread: c = jo+8k (lo) and c+32 (hi), k=0..3.
  {
    int p = t >> 3, jo = t & 7;
    float slo[4] = {0.f, 0.f, 0.f, 0.f};
    float shi[4] = {0.f, 0.f, 0.f, 0.f};
#pragma unroll
    for (int wr = 0; wr < 8; ++wr) {
      const unsigned* Pu = (const unsigned*)h1s + (size_t)wr * 2176 + p * 34 + jo;
#pragma unroll
      for (int k = 0; k < 4; ++k) {
        unsigned v = Pu[8 * k];
        slo[k] += __uint_as_float(v << 16);
        shi[k] += __uint_as_float(v & 0xFFFF0000u);
      }
    }
    float s = 0.f, g = 0.f;
#pragma unroll
    for (int k = 0; k < 4; ++k) {
      int c = jo + 8 * k;
      float e0 = __expf(slo[k] + bi3s[c]);
      float e1 = __expf(shi[k] + bi3s[c + 32]);
      s += e0 + e1;
      g += e0 * ab[c] + e1 * ab[c + 32];
    }
#pragma unroll
    for (int mm = 4; mm >= 1; mm >>= 1) { s += __shfl_xor(s, mm); g += __shfl_xor(g, mm); }
    if (jo == 0) out[b * 64 + p] = g / s;
  }
}

extern "C" void kernel_launch(void* const* d_in, const int* in_sizes, int n_in,
                              void* d_out, int out_size, void* d_ws, size_t ws_size,
                              hipStream_t stream) {
  const float* a_bits     = (const float*)d_in[0];
  const float* shift_bits = (const float*)d_in[1];
  const float* W1  = (const float*)d_in[2];
  const float* b1  = (const float*)d_in[3];
  const float* g1  = (const float*)d_in[4];
  const float* be1 = (const float*)d_in[5];
  const float* W2  = (const float*)d_in[6];
  const float* b2  = (const float*)d_in[7];
  const float* g2  = (const float*)d_in[8];
  const float* be2 = (const float*)d_in[9];
  const float* W3  = (const float*)d_in[10];
  const float* b3  = (const float*)d_in[11];
  const float* Wi1 = (const float*)d_in[12];
  const float* bi1 = (const float*)d_in[13];
  const float* Wi2 = (const float*)d_in[14];
  const float* bi2 = (const float*)d_in[15];
  const float* Wi3 = (const float*)d_in[16];
  const float* bi3 = (const float*)d_in[17];
  float* out = (float*)d_out;

  // ws layout: sp fp32 [B][512] (8MB) | W2f (512KB) | W1b (64KB) | W3b (64KB)
  //            | Wi1sb (64KB) | Wi1posTb bf16 (64KB) | Wi2f32 (512KB) | Wi3g (64KB)
  float* sp = (float*)d_ws;
  ushort_t* W2f = (ushort_t*)((char*)d_ws + (size_t)B_N * HID * 4);
  ushort_t* W1b = W2f + 512 * 512;
  ushort_t* W3b = W1b + 512 * 64;
  ushort_t* Wi1sb = W3b + 64 * 512;
  ushort_t* Wi1posTb = Wi1sb + 512 * 64;
  ushort_t* Wi2f32 = Wi1posTb + 64 * 512;
  ushort_t* Wi3g = Wi2f32 + 512 * 512;

  prep_kernel<<<1024, 256, 0, stream>>>(Wi2, Wi3, Wi1, W1, W2, W3,
                                        Wi1posTb, W1b, W2f, W3b, Wi1sb, Wi2f32, Wi3g);
  shift2_kernel<<<B_N / BT, 256, 0, stream>>>(shift_bits, W1b, b1, g1, be1,
                                              W2f, b2, g2, be2, W3b, b3, Wi1sb, bi1, sp);
  big12_kernel<<<B_N, 512, 0, stream>>>(a_bits, sp, Wi1posTb, Wi2f32, Wi3g, bi2, bi3, out);
}

// Round 14
// 199.634 us; speedup vs baseline: 1.1727x; 1.0080x over previous
//
#include <hip/hip_runtime.h>
#include <hip/hip_bf16.h>
#include <math.h>

// Problem constants
#define B_N 4096
#define BITSN 64
#define HID 512
#define EPSV 1e-5f
#define BT 16   // batch rows per shift2 block

typedef unsigned short ushort_t;
typedef __attribute__((ext_vector_type(8))) short bf16x8;
typedef __attribute__((ext_vector_type(4))) float f32x4;
typedef __attribute__((ext_vector_type(16))) float f32x16;

__device__ __forceinline__ ushort_t f2bf(float f) {
  unsigned u = __float_as_uint(f);
  u += 0x7FFF + ((u >> 16) & 1);   // round-to-nearest-even
  return (ushort_t)(u >> 16);
}

__device__ __forceinline__ unsigned pack2bf(float lo, float hi) {
  union { __hip_bfloat162 h; unsigned u; } cv;
  cv.h = __float22bfloat162_rn(make_float2(lo, hi));  // v_cvt_pk_bf16_f32
  return cv.u;
}

__device__ __forceinline__ float bf2f(short v) {
  return __uint_as_float(((unsigned)(unsigned short)v) << 16);
}

// ---------------- prep: bf16 copies, transposes, FRAGMENT-ORDER weights ----
// Wi2f32: 32x32x16 frag order (big GEMM1 B). Frag (ks 0..31, ct 0..15) lane l:
//   Wi2[ct*32 + (l&31)][ks*16 + (l>>5)*8 + j].
// W2f: 16x16x32 frag order (shift2 GEMM2 B, verified R5/R10).
// Wi3g: big GEMM2 B in the (e,hi)->c permutation the in-register h2 pack
//   produces (verified R8/R10).
// Wi1posTb: bf16 pos_part transpose [64][512].
__global__ __launch_bounds__(256) void prep_kernel(
    const float* __restrict__ Wi2, const float* __restrict__ Wi3,
    const float* __restrict__ Wi1, const float* __restrict__ W1,
    const float* __restrict__ W2, const float* __restrict__ W3,
    ushort_t* __restrict__ Wi1posTb, ushort_t* __restrict__ W1b,
    ushort_t* __restrict__ W2f, ushort_t* __restrict__ W3b,
    ushort_t* __restrict__ Wi1sb, ushort_t* __restrict__ Wi2f32,
    ushort_t* __restrict__ Wi3g) {
  int idx = blockIdx.x * 256 + threadIdx.x;
  if (idx < 512 * 512) {
    // W2f (16x16x32 frag order) for shift2 GEMM2
    {
      int j = idx & 7, lane = (idx >> 3) & 63;
      int ct = (idx >> 9) & 31, ks = idx >> 14;
      int c = ct * 16 + (lane & 15);
      int k = ks * 32 + (lane >> 4) * 8 + j;
      W2f[idx] = f2bf(W2[c * 512 + k]);
    }
    // Wi2f32 (32x32x16 frag order) for big GEMM1
    {
      int j = idx & 7, lane = (idx >> 3) & 63;
      int ct = (idx >> 9) & 15, ks = idx >> 13;
      int c = ct * 32 + (lane & 31);
      int k = ks * 16 + (lane >> 5) * 8 + j;
      Wi2f32[idx] = f2bf(Wi2[c * 512 + k]);
    }
  }
  if (idx < 64 * 512) {
    W3b[idx] = f2bf(W3[idx]);
    int p = idx >> 9, i = idx & 511;
    Wi1posTb[idx] = f2bf(Wi1[i * 128 + p]);   // pos_part[p][i] = Wi1[i][p], bf16
    // Wi3g dst-linear scatter (verified R8)
    int e = idx & 7, lane = (idx >> 3) & 63;
    int jt = (idx >> 9) & 1, h = (idx >> 10) & 1;
    int mc = (idx >> 11) & 1, w = idx >> 12;
    int jr = jt * 32 + (lane & 31);
    int c = w * 64 + mc * 32 + 16 * h + 4 * (lane >> 5) + (e & 3) + 8 * (e >> 2);
    Wi3g[idx] = f2bf(Wi3[jr * 512 + c]);
  }
  if (idx < 512 * 64) {
    W1b[idx] = f2bf(W1[idx]);                       // [512][64]
    int j = idx >> 6, k = idx & 63;
    Wi1sb[idx] = f2bf(Wi1[j * 128 + 64 + k]);       // shift cols of Wi1: [512][64]
  }
}

// ---------------- shift decoder, MFMA-batched: 16 rows/block ----------------
__global__ __launch_bounds__(256) void shift2_kernel(
    const float* __restrict__ shift_bits,
    const ushort_t* __restrict__ W1b, const float* __restrict__ b1,
    const float* __restrict__ g1, const float* __restrict__ be1,
    const ushort_t* __restrict__ W2f, const float* __restrict__ b2,
    const float* __restrict__ g2, const float* __restrict__ be2,
    const ushort_t* __restrict__ W3b, const float* __restrict__ b3,
    const ushort_t* __restrict__ Wi1sb, const float* __restrict__ bi1,
    float* __restrict__ sp) {
  __shared__ __align__(16) ushort_t hA[BT * 512];     // 16KB: h1 (post LN1+relu)
  __shared__ __align__(16) char reg2[32 * 1024];      // phase union
  __shared__ float b1s[512], g1s[512], be1s[512];
  __shared__ float b2s[512], g2s[512], be2s[512], bi1s[512];
  __shared__ float red[4][BT][2];
  __shared__ float b3s[64];

  ushort_t* sbt = (ushort_t*)reg2;                    // phase 1: shift_bits tile [16][64]
  ushort_t* h2  = (ushort_t*)reg2;                    // phase 3: h2 [16][512]
  float (*lg32)[68] = (float(*)[68])(reg2 + 16 * 1024);
  ushort_t* sb2 = (ushort_t*)(reg2 + 16 * 1024 + 16 * 68 * 4);  // soft [16][64]

  int b0 = blockIdx.x * BT;
  int t = threadIdx.x, w = t >> 6, l = t & 63, lg = l >> 4, l15 = l & 15;

  b1s[t] = b1[t];  b1s[t + 256] = b1[t + 256];
  g1s[t] = g1[t];  g1s[t + 256] = g1[t + 256];
  be1s[t] = be1[t]; be1s[t + 256] = be1[t + 256];
  b2s[t] = b2[t];  b2s[t + 256] = b2[t + 256];
  g2s[t] = g2[t];  g2s[t + 256] = g2[t + 256];
  be2s[t] = be2[t]; be2s[t + 256] = be2[t + 256];
  bi1s[t] = bi1[t]; bi1s[t + 256] = bi1[t + 256];
  if (t < 64) b3s[t] = b3[t];
  if (t < 128) {   // stage shift_bits tile -> bf16 swizzled
    int row = t >> 3, g = t & 7;
    const float* src = shift_bits + (size_t)(b0 + row) * 64 + g * 8;
    uint4 pk;
    pk.x = (unsigned)f2bf(src[0]) | ((unsigned)f2bf(src[1]) << 16);
    pk.y = (unsigned)f2bf(src[2]) | ((unsigned)f2bf(src[3]) << 16);
    pk.z = (unsigned)f2bf(src[4]) | ((unsigned)f2bf(src[5]) << 16);
    pk.w = (unsigned)f2bf(src[6]) | ((unsigned)f2bf(src[7]) << 16);
    *(uint4*)((char*)sbt + ((row * 128 + g * 16) ^ ((row & 7) << 4))) = pk;
  }
  __syncthreads();

  // ----- GEMM1: x1[16][512] = sbt @ W1^T ; wave w owns cols [w*128, w*128+128) -----
  f32x4 acc[8];
#pragma unroll
  for (int nt = 0; nt < 8; ++nt) acc[nt] = (f32x4){0.f, 0.f, 0.f, 0.f};
#pragma unroll
  for (int ks = 0; ks < 2; ++ks) {
    bf16x8 af = *(const bf16x8*)((char*)sbt + ((l15 * 128 + ks * 64 + lg * 16) ^ ((l15 & 7) << 4)));
#pragma unroll
    for (int nt = 0; nt < 8; ++nt) {
      int c = w * 128 + nt * 16 + l15;
      bf16x8 bfr = *(const bf16x8*)(W1b + (size_t)c * 64 + ks * 32 + lg * 8);
      acc[nt] = __builtin_amdgcn_mfma_f32_16x16x32_bf16(af, bfr, acc[nt], 0, 0, 0);
    }
  }
  // ----- LN1 + relu -> hA -----
  {
    float s[4] = {0.f, 0.f, 0.f, 0.f}, q[4] = {0.f, 0.f, 0.f, 0.f};
#pragma unroll
    for (int nt = 0; nt < 8; ++nt) {
      int c = w * 128 + nt * 16 + l15;
      float bb = b1s[c];
#pragma unroll
      for (int r = 0; r < 4; ++r) {
        float x = acc[nt][r] + bb;
        acc[nt][r] = x;
        s[r] += x; q[r] += x * x;
      }
    }
#pragma unroll
    for (int m = 8; m >= 1; m >>= 1)
#pragma unroll
      for (int r = 0; r < 4; ++r) { s[r] += __shfl_xor(s[r], m); q[r] += __shfl_xor(q[r], m); }
    if (l15 == 0)
#pragma unroll
      for (int r = 0; r < 4; ++r) { red[w][4 * lg + r][0] = s[r]; red[w][4 * lg + r][1] = q[r]; }
    __syncthreads();
    float mean[4], rs[4];
#pragma unroll
    for (int r = 0; r < 4; ++r) {
      int p = 4 * lg + r;
      float S = red[0][p][0] + red[1][p][0] + red[2][p][0] + red[3][p][0];
      float Q = red[0][p][1] + red[1][p][1] + red[2][p][1] + red[3][p][1];
      mean[r] = S * (1.0f / 512.0f);
      float var = Q * (1.0f / 512.0f) - mean[r] * mean[r];
      rs[r] = rsqrtf(var + EPSV);
    }
#pragma unroll
    for (int nt = 0; nt < 8; ++nt) {
      int c = w * 128 + nt * 16 + l15;
      float gg = g1s[c], bb = be1s[c];
#pragma unroll
      for (int r = 0; r < 4; ++r) {
        int p = 4 * lg + r;
        float v = (acc[nt][r] - mean[r]) * rs[r] * gg + bb;
        v = v > 0.f ? v : 0.f;
        *(ushort_t*)((char*)hA + ((p * 1024 + c * 2) ^ ((p & 7) << 4))) = f2bf(v);
      }
    }
  }
  __syncthreads();

  // ----- GEMM2: x2[16][512] = hA @ W2^T, frag-order W2f, barrier-free -----
#pragma unroll
  for (int nt = 0; nt < 8; ++nt) acc[nt] = (f32x4){0.f, 0.f, 0.f, 0.f};
  {
    const bf16x8* w2base = (const bf16x8*)W2f + ((size_t)(w * 8) * 64 + l);
#pragma unroll 2
    for (int step = 0; step < 16; ++step) {
      bf16x8 af = *(const bf16x8*)((char*)hA + ((l15 * 1024 + step * 64 + lg * 16) ^ ((l15 & 7) << 4)));
#pragma unroll
      for (int nt = 0; nt < 8; ++nt) {
        bf16x8 bfr = w2base[((size_t)step * 32 + nt) * 64];
        acc[nt] = __builtin_amdgcn_mfma_f32_16x16x32_bf16(af, bfr, acc[nt], 0, 0, 0);
      }
    }
  }
  __syncthreads();   // hA reads done; h2 region (reg2) free for overwrite
  // ----- LN2 + relu -> h2 -----
  {
    float s[4] = {0.f, 0.f, 0.f, 0.f}, q[4] = {0.f, 0.f, 0.f, 0.f};
#pragma unroll
    for (int nt = 0; nt < 8; ++nt) {
      int c = w * 128 + nt * 16 + l15;
      float bb = b2s[c];
#pragma unroll
      for (int r = 0; r < 4; ++r) {
        float x = acc[nt][r] + bb;
        acc[nt][r] = x;
        s[r] += x; q[r] += x * x;
      }
    }
#pragma unroll
    for (int m = 8; m >= 1; m >>= 1)
#pragma unroll
      for (int r = 0; r < 4; ++r) { s[r] += __shfl_xor(s[r], m); q[r] += __shfl_xor(q[r], m); }
    if (l15 == 0)
#pragma unroll
      for (int r = 0; r < 4; ++r) { red[w][4 * lg + r][0] = s[r]; red[w][4 * lg + r][1] = q[r]; }
    __syncthreads();
    float mean[4], rs[4];
#pragma unroll
    for (int r = 0; r < 4; ++r) {
      int p = 4 * lg + r;
      float S = red[0][p][0] + red[1][p][0] + red[2][p][0] + red[3][p][0];
      float Q = red[0][p][1] + red[1][p][1] + red[2][p][1] + red[3][p][1];
      mean[r] = S * (1.0f / 512.0f);
      float var = Q * (1.0f / 512.0f) - mean[r] * mean[r];
      rs[r] = rsqrtf(var + EPSV);
    }
#pragma unroll
    for (int nt = 0; nt < 8; ++nt) {
      int c = w * 128 + nt * 16 + l15;
      float gg = g2s[c], bb = be2s[c];
#pragma unroll
      for (int r = 0; r < 4; ++r) {
        int p = 4 * lg + r;
        float v = (acc[nt][r] - mean[r]) * rs[r] * gg + bb;
        v = v > 0.f ? v : 0.f;
        *(ushort_t*)((char*)h2 + ((p * 1024 + c * 2) ^ ((p & 7) << 4))) = f2bf(v);
      }
    }
  }
  __syncthreads();

  // ----- GEMM3: logits[16][64] = h2 @ W3^T ; wave w owns cols [16w,16w+16) -----
  {
    f32x4 a3 = (f32x4){0.f, 0.f, 0.f, 0.f};
#pragma unroll
    for (int ks = 0; ks < 16; ++ks) {
      bf16x8 af = *(const bf16x8*)((char*)h2 + ((l15 * 1024 + ks * 64 + lg * 16) ^ ((l15 & 7) << 4)));
      bf16x8 bfr = *(const bf16x8*)(W3b + (size_t)(w * 16 + l15) * 512 + ks * 32 + lg * 8);
      a3 = __builtin_amdgcn_mfma_f32_16x16x32_bf16(af, bfr, a3, 0, 0, 0);
    }
    int c = w * 16 + l15;
    float bb = b3s[c];
#pragma unroll
    for (int r = 0; r < 4; ++r) lg32[4 * lg + r][c] = a3[r] + bb;
  }
  __syncthreads();

  // ----- softmax over 64 logits -> sb2 (bf16, swizzled) -----
  {
    int r = t >> 4, j = t & 15;
    float v[4];
    float m = -1e30f;
#pragma unroll
    for (int mq = 0; mq < 4; ++mq) { v[mq] = lg32[r][mq * 16 + j]; m = fmaxf(m, v[mq]); }
#pragma unroll
    for (int mk = 8; mk >= 1; mk >>= 1) m = fmaxf(m, __shfl_xor(m, mk));
    float ssum = 0.f;
#pragma unroll
    for (int mq = 0; mq < 4; ++mq) { v[mq] = expf(v[mq] - m); ssum += v[mq]; }
#pragma unroll
    for (int mk = 8; mk >= 1; mk >>= 1) ssum += __shfl_xor(ssum, mk);
    float inv = 1.f / ssum;
#pragma unroll
    for (int mq = 0; mq < 4; ++mq) {
      int c = mq * 16 + j;
      *(ushort_t*)((char*)sb2 + ((r * 128 + c * 2) ^ ((r & 7) << 4))) = f2bf(v[mq] * inv);
    }
  }
  __syncthreads();

  // ----- GEMM4: sp[16][512] = soft @ Wi1shift^T + bi1 -----
  {
    f32x4 a4[8];
#pragma unroll
    for (int nt = 0; nt < 8; ++nt) a4[nt] = (f32x4){0.f, 0.f, 0.f, 0.f};
#pragma unroll
    for (int ks = 0; ks < 2; ++ks) {
      bf16x8 af = *(const bf16x8*)((char*)sb2 + ((l15 * 128 + ks * 64 + lg * 16) ^ ((l15 & 7) << 4)));
#pragma unroll
      for (int nt = 0; nt < 8; ++nt) {
        int c = w * 128 + nt * 16 + l15;
        bf16x8 bfr = *(const bf16x8*)(Wi1sb + (size_t)c * 64 + ks * 32 + lg * 8);
        a4[nt] = __builtin_amdgcn_mfma_f32_16x16x32_bf16(af, bfr, a4[nt], 0, 0, 0);
      }
    }
#pragma unroll
    for (int nt = 0; nt < 8; ++nt) {
      int c = w * 128 + nt * 16 + l15;
      float bb = bi1s[c];
#pragma unroll
      for (int r = 0; r < 4; ++r)
        sp[(size_t)(b0 + 4 * lg + r) * 512 + c] = a4[nt][r] + bb;
    }
  }
}

// ---------------- big13: big12 minus setprio, pitch-36 partials ----------------
// BM=64 (1 batch row), BN=512, 8 waves. h1[64][512] LDS (&15 swizzle), bf16 posT.
// GEMM1 = mfma(Wi2frag, h1frag), depth-4 B prefetch, NO setprio (A/B isolate,
// m190 evidence setprio hurts lockstep GEMM). h2 in regs -> pack (verified R8)
// -> GEMM2 in-reg 8-wave K-split. Partials: pair-packed uints at pitch 36
// (store bank (4p+q)%32: 2-way free; softmax read (4p+jo+8k)%32: <=2-3-way).
__global__ __launch_bounds__(512, 4) void big13_kernel(
    const float* __restrict__ a_bits, const float* __restrict__ sp,
    const ushort_t* __restrict__ posTb,
    const ushort_t* __restrict__ Wi2f32, const ushort_t* __restrict__ Wi3g,
    const float* __restrict__ bi2, const float* __restrict__ bi3,
    float* __restrict__ out) {
  // 8 regions x 64 rows x 36 uints = 73728 B; h1 phase uses first 65536 B.
  __shared__ __align__(16) ushort_t h1s[36864];
  __shared__ float bi2s[512];
  __shared__ float ab[64];
  __shared__ float bi3s[64];

  int b = blockIdx.x, t = threadIdx.x;
  int w = t >> 6, l = t & 63;
  int l31 = l & 31, hi = l >> 5;

  bi2s[t] = bi2[t];
  if (t < 64) { ab[t] = a_bits[b * 64 + t]; bi3s[t] = bi3[t]; }

  // ---- phase 0: h1[64][512] = relu(sp[b] + pos) -> LDS bf16, swizzled, ONCE ----
  {
    const float* sprow = sp + (size_t)b * 512 + l * 8;
    float4 s0 = *(const float4*)(sprow);
    float4 s1 = *(const float4*)(sprow + 4);
#pragma unroll
    for (int g = 0; g < 8; ++g) {
      int p = g * 8 + w;                    // wave w covers rows {w, 8+w, ..., 56+w}
      bf16x8 pr = *(const bf16x8*)(posTb + (size_t)p * 512 + l * 8);
      float v0 = fmaxf(s0.x + bf2f(pr[0]), 0.f), v1 = fmaxf(s0.y + bf2f(pr[1]), 0.f);
      float v2 = fmaxf(s0.z + bf2f(pr[2]), 0.f), v3 = fmaxf(s0.w + bf2f(pr[3]), 0.f);
      float v4 = fmaxf(s1.x + bf2f(pr[4]), 0.f), v5 = fmaxf(s1.y + bf2f(pr[5]), 0.f);
      float v6 = fmaxf(s1.z + bf2f(pr[6]), 0.f), v7 = fmaxf(s1.w + bf2f(pr[7]), 0.f);
      uint4 pk;
      pk.x = pack2bf(v0, v1); pk.y = pack2bf(v2, v3);
      pk.z = pack2bf(v4, v5); pk.w = pack2bf(v6, v7);
      *(uint4*)((char*)h1s + ((p * 1024 + l * 16) ^ ((p & 15) << 4))) = pk;
    }
  }
  __syncthreads();

  // ---- GEMM1: mfma(Wi2, h1) ; 32x32x16, depth-4 B prefetch, barrier-free ----
  f32x16 acc[2][2];   // acc[mc][np]: reg<->c (c-tile mc), lane<->p (p-tile np)
#pragma unroll
  for (int mc = 0; mc < 2; ++mc)
#pragma unroll
    for (int np = 0; np < 2; ++np)
#pragma unroll
      for (int r = 0; r < 16; ++r) acc[mc][np][r] = 0.f;

  {
    const bf16x8* bbase = (const bf16x8*)Wi2f32 + ((size_t)(2 * w) * 64 + l);
    bf16x8 wf[4][2];
#pragma unroll
    for (int d = 0; d < 4; ++d) {
      wf[d][0] = bbase[(size_t)d * 1024];
      wf[d][1] = bbase[(size_t)d * 1024 + 64];
    }
    for (int kb = 0; kb < 8; ++kb) {
#pragma unroll
      for (int d = 0; d < 4; ++d) {
        int ks = kb * 4 + d;
        bf16x8 w0 = wf[d][0], w1 = wf[d][1];
        if (kb < 7) {
          wf[d][0] = bbase[(size_t)(ks + 4) * 1024];
          wf[d][1] = bbase[(size_t)(ks + 4) * 1024 + 64];
        }
        int row0 = l31, row1 = 32 + l31;
        bf16x8 h0 = *(const bf16x8*)((char*)h1s + ((row0 * 1024 + ks * 32 + hi * 16) ^ ((row0 & 15) << 4)));
        bf16x8 h1v = *(const bf16x8*)((char*)h1s + ((row1 * 1024 + ks * 32 + hi * 16) ^ ((row1 & 15) << 4)));
        acc[0][0] = __builtin_amdgcn_mfma_f32_32x32x16_bf16(w0, h0, acc[0][0], 0, 0, 0);
        acc[0][1] = __builtin_amdgcn_mfma_f32_32x32x16_bf16(w0, h1v, acc[0][1], 0, 0, 0);
        acc[1][0] = __builtin_amdgcn_mfma_f32_32x32x16_bf16(w1, h0, acc[1][0], 0, 0, 0);
        acc[1][1] = __builtin_amdgcn_mfma_f32_32x32x16_bf16(w1, h1v, acc[1][1], 0, 0, 0);
      }
    }
  }

  // ---- h2 = relu(acc + bi2), pack to bf16 A-frags in regs (layout verified R8) ----
  bf16x8 pkf[2][2][2];   // [np][mc][h]
#pragma unroll
  for (int mc = 0; mc < 2; ++mc) {
    float bia[16];
#pragma unroll
    for (int rq = 0; rq < 4; ++rq) {
      int c0 = w * 64 + mc * 32 + 8 * rq + 4 * hi;
      float4 bi4 = *(const float4*)(bi2s + c0);
      bia[4 * rq + 0] = bi4.x; bia[4 * rq + 1] = bi4.y;
      bia[4 * rq + 2] = bi4.z; bia[4 * rq + 3] = bi4.w;
    }
#pragma unroll
    for (int np = 0; np < 2; ++np) {
      float hv[16];
#pragma unroll
      for (int r = 0; r < 16; ++r) hv[r] = fmaxf(acc[mc][np][r] + bia[r], 0.f);
#pragma unroll
      for (int h = 0; h < 2; ++h) {
        unsigned d0 = pack2bf(hv[8 * h + 0], hv[8 * h + 1]);
        unsigned d1 = pack2bf(hv[8 * h + 2], hv[8 * h + 3]);
        unsigned d2 = pack2bf(hv[8 * h + 4], hv[8 * h + 5]);
        unsigned d3 = pack2bf(hv[8 * h + 6], hv[8 * h + 7]);
        union { unsigned u[4]; bf16x8 v; } cv;
        cv.u[0] = d0; cv.u[1] = d1; cv.u[2] = d2; cv.u[3] = d3;
        pkf[np][mc][h] = cv.v;
      }
    }
  }
  __syncthreads();   // all waves done reading h1s -> safe to reuse as partials

  // ---- GEMM2: partial logits over this wave's 64-c chunk, fully in-reg ----
  f32x16 l00, l01, l10, l11;
#pragma unroll
  for (int r = 0; r < 16; ++r) { l00[r] = 0.f; l01[r] = 0.f; l10[r] = 0.f; l11[r] = 0.f; }
  {
    const bf16x8* gbase = (const bf16x8*)Wi3g + ((size_t)w * 8 * 64 + l);
#pragma unroll
    for (int mc = 0; mc < 2; ++mc) {
#pragma unroll
      for (int h = 0; h < 2; ++h) {
        bf16x8 g0 = gbase[((mc * 2 + h) * 2 + 0) * 64];
        bf16x8 g1 = gbase[((mc * 2 + h) * 2 + 1) * 64];
        l00 = __builtin_amdgcn_mfma_f32_32x32x16_bf16(pkf[0][mc][h], g0, l00, 0, 0, 0);
        l01 = __builtin_amdgcn_mfma_f32_32x32x16_bf16(pkf[0][mc][h], g1, l01, 0, 0, 0);
        l10 = __builtin_amdgcn_mfma_f32_32x32x16_bf16(pkf[1][mc][h], g0, l10, 0, 0, 0);
        l11 = __builtin_amdgcn_mfma_f32_32x32x16_bf16(pkf[1][mc][h], g1, l11, 0, 0, 0);
      }
    }
  }

  // ---- pair-packed partial store: Pu_w[p*36 + q] = (P[p][q], P[p][q+32]) ----
  // D: lane<->j (jt*32+l31 -> l00/l10 j=l31, l01/l11 j=32+l31), reg<->p.
  // Pitch 36: store bank (4p+q)%32, q=l31 distinct per half-wave -> 2-way free.
  {
    unsigned* Pu = (unsigned*)h1s + (size_t)w * 2304;   // 64*36 uints per wave
#pragma unroll
    for (int r = 0; r < 16; ++r) {
      int p0 = (r & 3) + 8 * (r >> 2) + 4 * hi;
      int p1 = p0 + 32;
      Pu[p0 * 36 + l31] = pack2bf(l00[r], l01[r]);
      Pu[p1 * 36 + l31] = pack2bf(l10[r], l11[r]);
    }
  }
  __syncthreads();

  // ---- max-free softmax + gather: thread (p=t>>3, jo=t&7) sums 8 regions ----
  // Column set per thread: c = jo+8k (lo) and c+32 (hi), k=0..3.
  {
    int p = t >> 3, jo = t & 7;
    float slo[4] = {0.f, 0.f, 0.f, 0.f};
    float shi[4] = {0.f, 0.f, 0.f, 0.f};
#pragma unroll
    for (int wr = 0; wr < 8; ++wr) {
      const unsigned* Pu = (const unsigned*)h1s + (size_t)wr * 2304 + p * 36 + jo;
#pragma unroll
      for (int k = 0; k < 4; ++k) {
        unsigned v = Pu[8 * k];
        slo[k] += __uint_as_float(v << 16);
        shi[k] += __uint_as_float(v & 0xFFFF0000u);
      }
    }
    float s = 0.f, g = 0.f;
#pragma unroll
    for (int k = 0; k < 4; ++k) {
      int c = jo + 8 * k;
      float e0 = __expf(slo[k] + bi3s[c]);
      float e1 = __expf(shi[k] + bi3s[c + 32]);
      s += e0 + e1;
      g += e0 * ab[c] + e1 * ab[c + 32];
    }
#pragma unroll
    for (int mm = 4; mm >= 1; mm >>= 1) { s += __shfl_xor(s, mm); g += __shfl_xor(g, mm); }
    if (jo == 0) out[b * 64 + p] = g / s;
  }
}

extern "C" void kernel_launch(void* const* d_in, const int* in_sizes, int n_in,
                              void* d_out, int out_size, void* d_ws, size_t ws_size,
                              hipStream_t stream) {
  const float* a_bits     = (const float*)d_in[0];
  const float* shift_bits = (const float*)d_in[1];
  const float* W1  = (const float*)d_in[2];
  const float* b1  = (const float*)d_in[3];
  const float* g1  = (const float*)d_in[4];
  const float* be1 = (const float*)d_in[5];
  const float* W2  = (const float*)d_in[6];
  const float* b2  = (const float*)d_in[7];
  const float* g2  = (const float*)d_in[8];
  const float* be2 = (const float*)d_in[9];
  const float* W3  = (const float*)d_in[10];
  const float* b3  = (const float*)d_in[11];
  const float* Wi1 = (const float*)d_in[12];
  const float* bi1 = (const float*)d_in[13];
  const float* Wi2 = (const float*)d_in[14];
  const float* bi2 = (const float*)d_in[15];
  const float* Wi3 = (const float*)d_in[16];
  const float* bi3 = (const float*)d_in[17];
  float* out = (float*)d_out;

  // ws layout: sp fp32 [B][512] (8MB) | W2f (512KB) | W1b (64KB) | W3b (64KB)
  //            | Wi1sb (64KB) | Wi1posTb bf16 (64KB) | Wi2f32 (512KB) | Wi3g (64KB)
  float* sp = (float*)d_ws;
  ushort_t* W2f = (ushort_t*)((char*)d_ws + (size_t)B_N * HID * 4);
  ushort_t* W1b = W2f + 512 * 512;
  ushort_t* W3b = W1b + 512 * 64;
  ushort_t* Wi1sb = W3b + 64 * 512;
  ushort_t* Wi1posTb = Wi1sb + 512 * 64;
  ushort_t* Wi2f32 = Wi1posTb + 64 * 512;
  ushort_t* Wi3g = Wi2f32 + 512 * 512;

  prep_kernel<<<1024, 256, 0, stream>>>(Wi2, Wi3, Wi1, W1, W2, W3,
                                        Wi1posTb, W1b, W2f, W3b, Wi1sb, Wi2f32, Wi3g);
  shift2_kernel<<<B_N / BT, 256, 0, stream>>>(shift_bits, W1b, b1, g1, be1,
                                              W2f, b2, g2, be2, W3b, b3, Wi1sb, bi1, sp);
  big13_kernel<<<B_N, 512, 0, stream>>>(a_bits, sp, Wi1posTb, Wi2f32, Wi3g, bi2, bi3, out);
}

// Round 15
// 192.737 us; speedup vs baseline: 1.2147x; 1.0358x over previous
//
#include <hip/hip_runtime.h>
#include <hip/hip_bf16.h>
#include <math.h>

// Problem constants
#define B_N 4096
#define BITSN 64
#define HID 512
#define EPSV 1e-5f
#define BT 16   // batch rows per shift block

typedef unsigned short ushort_t;
typedef __attribute__((ext_vector_type(8))) short bf16x8;
typedef __attribute__((ext_vector_type(4))) float f32x4;
typedef __attribute__((ext_vector_type(16))) float f32x16;

__device__ __forceinline__ ushort_t f2bf(float f) {
  unsigned u = __float_as_uint(f);
  u += 0x7FFF + ((u >> 16) & 1);   // round-to-nearest-even
  return (ushort_t)(u >> 16);
}

__device__ __forceinline__ unsigned pack2bf(float lo, float hi) {
  union { __hip_bfloat162 h; unsigned u; } cv;
  cv.h = __float22bfloat162_rn(make_float2(lo, hi));  // v_cvt_pk_bf16_f32
  return cv.u;
}

__device__ __forceinline__ float bf2f(short v) {
  return __uint_as_float(((unsigned)(unsigned short)v) << 16);
}

// ---------------- prep: bf16 copies, transposes, FRAGMENT-ORDER weights ----
__global__ __launch_bounds__(256) void prep_kernel(
    const float* __restrict__ Wi2, const float* __restrict__ Wi3,
    const float* __restrict__ Wi1, const float* __restrict__ W1,
    const float* __restrict__ W2, const float* __restrict__ W3,
    ushort_t* __restrict__ Wi1posTb, ushort_t* __restrict__ W1b,
    ushort_t* __restrict__ W2f, ushort_t* __restrict__ W3b,
    ushort_t* __restrict__ Wi1sb, ushort_t* __restrict__ Wi2f32,
    ushort_t* __restrict__ Wi3g) {
  int idx = blockIdx.x * 256 + threadIdx.x;
  if (idx < 512 * 512) {
    // W2f (16x16x32 frag order) for shift GEMM2
    {
      int j = idx & 7, lane = (idx >> 3) & 63;
      int ct = (idx >> 9) & 31, ks = idx >> 14;
      int c = ct * 16 + (lane & 15);
      int k = ks * 32 + (lane >> 4) * 8 + j;
      W2f[idx] = f2bf(W2[c * 512 + k]);
    }
    // Wi2f32 (32x32x16 frag order) for big GEMM1
    {
      int j = idx & 7, lane = (idx >> 3) & 63;
      int ct = (idx >> 9) & 15, ks = idx >> 13;
      int c = ct * 32 + (lane & 31);
      int k = ks * 16 + (lane >> 5) * 8 + j;
      Wi2f32[idx] = f2bf(Wi2[c * 512 + k]);
    }
  }
  if (idx < 64 * 512) {
    W3b[idx] = f2bf(W3[idx]);
    int p = idx >> 9, i = idx & 511;
    Wi1posTb[idx] = f2bf(Wi1[i * 128 + p]);   // pos_part[p][i] = Wi1[i][p], bf16
    // Wi3g dst-linear scatter (verified R8)
    int e = idx & 7, lane = (idx >> 3) & 63;
    int jt = (idx >> 9) & 1, h = (idx >> 10) & 1;
    int mc = (idx >> 11) & 1, w = idx >> 12;
    int jr = jt * 32 + (lane & 31);
    int c = w * 64 + mc * 32 + 16 * h + 4 * (lane >> 5) + (e & 3) + 8 * (e >> 2);
    Wi3g[idx] = f2bf(Wi3[jr * 512 + c]);
  }
  if (idx < 512 * 64) {
    W1b[idx] = f2bf(W1[idx]);                       // [512][64]
    int j = idx >> 6, k = idx & 63;
    Wi1sb[idx] = f2bf(Wi1[j * 128 + 64 + k]);       // shift cols of Wi1: [512][64]
  }
}

// ---------------- shift decoder, 8-wave (512 threads): halved phase chain ----
// 16 rows/block, 256 blocks, ~63KB LDS -> 2 blocks/CU. Wave w owns 64 cols
// (nt 0..3) in GEMM1/LN/GEMM2/GEMM4; GEMM3 split (j-tile w&3, K-half w>>2)
// with 2-way partial sum in lgp.
__global__ __launch_bounds__(512) void shift3_kernel(
    const float* __restrict__ shift_bits,
    const ushort_t* __restrict__ W1b, const float* __restrict__ b1,
    const float* __restrict__ g1, const float* __restrict__ be1,
    const ushort_t* __restrict__ W2f, const float* __restrict__ b2,
    const float* __restrict__ g2, const float* __restrict__ be2,
    const ushort_t* __restrict__ W3b, const float* __restrict__ b3,
    const ushort_t* __restrict__ Wi1sb, const float* __restrict__ bi1,
    float* __restrict__ sp) {
  __shared__ __align__(16) ushort_t hA[BT * 512];     // 16KB: h1 (post LN1+relu)
  __shared__ __align__(16) char reg2[32 * 1024];      // phase union
  __shared__ float b1s[512], g1s[512], be1s[512];
  __shared__ float b2s[512], g2s[512], be2s[512], bi1s[512];
  __shared__ float red[8][BT][2];
  __shared__ float b3s[64];

  ushort_t* sbt = (ushort_t*)reg2;                    // phase 1: shift_bits tile [16][64]
  ushort_t* h2  = (ushort_t*)reg2;                    // phase 3: h2 [16][512]
  float (*lgp)[16][68] = (float(*)[16][68])(reg2 + 16 * 1024);  // 2 K-half partials
  ushort_t* sb2 = (ushort_t*)(reg2 + 16 * 1024 + 2 * 16 * 68 * 4);  // soft [16][64]

  int b0 = blockIdx.x * BT;
  int t = threadIdx.x, w = t >> 6, l = t & 63, lg = l >> 4, l15 = l & 15;

  b1s[t] = b1[t];  g1s[t] = g1[t];  be1s[t] = be1[t];
  b2s[t] = b2[t];  g2s[t] = g2[t];  be2s[t] = be2[t];
  bi1s[t] = bi1[t];
  if (t < 64) b3s[t] = b3[t];
  if (t < 128) {   // stage shift_bits tile -> bf16 swizzled
    int row = t >> 3, g = t & 7;
    const float* src = shift_bits + (size_t)(b0 + row) * 64 + g * 8;
    uint4 pk;
    pk.x = (unsigned)f2bf(src[0]) | ((unsigned)f2bf(src[1]) << 16);
    pk.y = (unsigned)f2bf(src[2]) | ((unsigned)f2bf(src[3]) << 16);
    pk.z = (unsigned)f2bf(src[4]) | ((unsigned)f2bf(src[5]) << 16);
    pk.w = (unsigned)f2bf(src[6]) | ((unsigned)f2bf(src[7]) << 16);
    *(uint4*)((char*)sbt + ((row * 128 + g * 16) ^ ((row & 7) << 4))) = pk;
  }
  __syncthreads();

  // ----- GEMM1: x1[16][512] = sbt @ W1^T ; wave w owns cols [w*64, w*64+64) -----
  f32x4 acc[4];
#pragma unroll
  for (int nt = 0; nt < 4; ++nt) acc[nt] = (f32x4){0.f, 0.f, 0.f, 0.f};
#pragma unroll
  for (int ks = 0; ks < 2; ++ks) {
    bf16x8 af = *(const bf16x8*)((char*)sbt + ((l15 * 128 + ks * 64 + lg * 16) ^ ((l15 & 7) << 4)));
#pragma unroll
    for (int nt = 0; nt < 4; ++nt) {
      int c = w * 64 + nt * 16 + l15;
      bf16x8 bfr = *(const bf16x8*)(W1b + (size_t)c * 64 + ks * 32 + lg * 8);
      acc[nt] = __builtin_amdgcn_mfma_f32_16x16x32_bf16(af, bfr, acc[nt], 0, 0, 0);
    }
  }
  // ----- LN1 + relu -> hA -----
  {
    float s[4] = {0.f, 0.f, 0.f, 0.f}, q[4] = {0.f, 0.f, 0.f, 0.f};
#pragma unroll
    for (int nt = 0; nt < 4; ++nt) {
      int c = w * 64 + nt * 16 + l15;
      float bb = b1s[c];
#pragma unroll
      for (int r = 0; r < 4; ++r) {
        float x = acc[nt][r] + bb;
        acc[nt][r] = x;
        s[r] += x; q[r] += x * x;
      }
    }
#pragma unroll
    for (int m = 8; m >= 1; m >>= 1)
#pragma unroll
      for (int r = 0; r < 4; ++r) { s[r] += __shfl_xor(s[r], m); q[r] += __shfl_xor(q[r], m); }
    if (l15 == 0)
#pragma unroll
      for (int r = 0; r < 4; ++r) { red[w][4 * lg + r][0] = s[r]; red[w][4 * lg + r][1] = q[r]; }
    __syncthreads();
    float mean[4], rs[4];
#pragma unroll
    for (int r = 0; r < 4; ++r) {
      int p = 4 * lg + r;
      float S = 0.f, Q = 0.f;
#pragma unroll
      for (int ww = 0; ww < 8; ++ww) { S += red[ww][p][0]; Q += red[ww][p][1]; }
      mean[r] = S * (1.0f / 512.0f);
      float var = Q * (1.0f / 512.0f) - mean[r] * mean[r];
      rs[r] = rsqrtf(var + EPSV);
    }
#pragma unroll
    for (int nt = 0; nt < 4; ++nt) {
      int c = w * 64 + nt * 16 + l15;
      float gg = g1s[c], bb = be1s[c];
#pragma unroll
      for (int r = 0; r < 4; ++r) {
        int p = 4 * lg + r;
        float v = (acc[nt][r] - mean[r]) * rs[r] * gg + bb;
        v = v > 0.f ? v : 0.f;
        *(ushort_t*)((char*)hA + ((p * 1024 + c * 2) ^ ((p & 7) << 4))) = f2bf(v);
      }
    }
  }
  __syncthreads();

  // ----- GEMM2: x2[16][512] = hA @ W2^T, frag-order W2f, barrier-free -----
#pragma unroll
  for (int nt = 0; nt < 4; ++nt) acc[nt] = (f32x4){0.f, 0.f, 0.f, 0.f};
  {
    const bf16x8* w2base = (const bf16x8*)W2f + ((size_t)(w * 4) * 64 + l);
#pragma unroll 2
    for (int step = 0; step < 16; ++step) {
      bf16x8 af = *(const bf16x8*)((char*)hA + ((l15 * 1024 + step * 64 + lg * 16) ^ ((l15 & 7) << 4)));
#pragma unroll
      for (int nt = 0; nt < 4; ++nt) {
        bf16x8 bfr = w2base[((size_t)step * 32 + nt) * 64];
        acc[nt] = __builtin_amdgcn_mfma_f32_16x16x32_bf16(af, bfr, acc[nt], 0, 0, 0);
      }
    }
  }
  __syncthreads();   // hA reads done; h2 region (reg2) free for overwrite
  // ----- LN2 + relu -> h2 -----
  {
    float s[4] = {0.f, 0.f, 0.f, 0.f}, q[4] = {0.f, 0.f, 0.f, 0.f};
#pragma unroll
    for (int nt = 0; nt < 4; ++nt) {
      int c = w * 64 + nt * 16 + l15;
      float bb = b2s[c];
#pragma unroll
      for (int r = 0; r < 4; ++r) {
        float x = acc[nt][r] + bb;
        acc[nt][r] = x;
        s[r] += x; q[r] += x * x;
      }
    }
#pragma unroll
    for (int m = 8; m >= 1; m >>= 1)
#pragma unroll
      for (int r = 0; r < 4; ++r) { s[r] += __shfl_xor(s[r], m); q[r] += __shfl_xor(q[r], m); }
    if (l15 == 0)
#pragma unroll
      for (int r = 0; r < 4; ++r) { red[w][4 * lg + r][0] = s[r]; red[w][4 * lg + r][1] = q[r]; }
    __syncthreads();
    float mean[4], rs[4];
#pragma unroll
    for (int r = 0; r < 4; ++r) {
      int p = 4 * lg + r;
      float S = 0.f, Q = 0.f;
#pragma unroll
      for (int ww = 0; ww < 8; ++ww) { S += red[ww][p][0]; Q += red[ww][p][1]; }
      mean[r] = S * (1.0f / 512.0f);
      float var = Q * (1.0f / 512.0f) - mean[r] * mean[r];
      rs[r] = rsqrtf(var + EPSV);
    }
#pragma unroll
    for (int nt = 0; nt < 4; ++nt) {
      int c = w * 64 + nt * 16 + l15;
      float gg = g2s[c], bb = be2s[c];
#pragma unroll
      for (int r = 0; r < 4; ++r) {
        int p = 4 * lg + r;
        float v = (acc[nt][r] - mean[r]) * rs[r] * gg + bb;
        v = v > 0.f ? v : 0.f;
        *(ushort_t*)((char*)h2 + ((p * 1024 + c * 2) ^ ((p & 7) << 4))) = f2bf(v);
      }
    }
  }
  __syncthreads();

  // ----- GEMM3: logits[16][64] = h2 @ W3^T ; wave w = (j-tile w&3, K-half w>>2) -----
  {
    int jt = w & 3, kh = w >> 2;
    f32x4 a3 = (f32x4){0.f, 0.f, 0.f, 0.f};
#pragma unroll
    for (int s8 = 0; s8 < 8; ++s8) {
      int ks = kh * 8 + s8;
      bf16x8 af = *(const bf16x8*)((char*)h2 + ((l15 * 1024 + ks * 64 + lg * 16) ^ ((l15 & 7) << 4)));
      bf16x8 bfr = *(const bf16x8*)(W3b + (size_t)(jt * 16 + l15) * 512 + ks * 32 + lg * 8);
      a3 = __builtin_amdgcn_mfma_f32_16x16x32_bf16(af, bfr, a3, 0, 0, 0);
    }
    int c = jt * 16 + l15;
#pragma unroll
    for (int r = 0; r < 4; ++r) lgp[kh][4 * lg + r][c] = a3[r];
  }
  __syncthreads();

  // ----- softmax over 64 logits -> sb2 (bf16, swizzled); 512 thr: 2 cols each -----
  {
    int r = t >> 5, j2 = t & 31;
    float v[2];
    float m = -1e30f;
#pragma unroll
    for (int mq = 0; mq < 2; ++mq) {
      int c = mq * 32 + j2;
      v[mq] = b3s[c] + lgp[0][r][c] + lgp[1][r][c];
      m = fmaxf(m, v[mq]);
    }
#pragma unroll
    for (int mk = 16; mk >= 1; mk >>= 1) m = fmaxf(m, __shfl_xor(m, mk));
    float ssum = 0.f;
#pragma unroll
    for (int mq = 0; mq < 2; ++mq) { v[mq] = __expf(v[mq] - m); ssum += v[mq]; }
#pragma unroll
    for (int mk = 16; mk >= 1; mk >>= 1) ssum += __shfl_xor(ssum, mk);
    float inv = 1.f / ssum;
#pragma unroll
    for (int mq = 0; mq < 2; ++mq) {
      int c = mq * 32 + j2;
      *(ushort_t*)((char*)sb2 + ((r * 128 + c * 2) ^ ((r & 7) << 4))) = f2bf(v[mq] * inv);
    }
  }
  __syncthreads();

  // ----- GEMM4: sp[16][512] = soft @ Wi1shift^T + bi1 ; wave w owns 64 cols -----
  {
    f32x4 a4[4];
#pragma unroll
    for (int nt = 0; nt < 4; ++nt) a4[nt] = (f32x4){0.f, 0.f, 0.f, 0.f};
#pragma unroll
    for (int ks = 0; ks < 2; ++ks) {
      bf16x8 af = *(const bf16x8*)((char*)sb2 + ((l15 * 128 + ks * 64 + lg * 16) ^ ((l15 & 7) << 4)));
#pragma unroll
      for (int nt = 0; nt < 4; ++nt) {
        int c = w * 64 + nt * 16 + l15;
        bf16x8 bfr = *(const bf16x8*)(Wi1sb + (size_t)c * 64 + ks * 32 + lg * 8);
        a4[nt] = __builtin_amdgcn_mfma_f32_16x16x32_bf16(af, bfr, a4[nt], 0, 0, 0);
      }
    }
#pragma unroll
    for (int nt = 0; nt < 4; ++nt) {
      int c = w * 64 + nt * 16 + l15;
      float bb = bi1s[c];
#pragma unroll
      for (int r = 0; r < 4; ++r)
        sp[(size_t)(b0 + 4 * lg + r) * 512 + c] = a4[nt][r] + bb;
    }
  }
}

// ---------------- big13 (unchanged, R14 best): no setprio, pitch-36 partials ----
__global__ __launch_bounds__(512, 4) void big13_kernel(
    const float* __restrict__ a_bits, const float* __restrict__ sp,
    const ushort_t* __restrict__ posTb,
    const ushort_t* __restrict__ Wi2f32, const ushort_t* __restrict__ Wi3g,
    const float* __restrict__ bi2, const float* __restrict__ bi3,
    float* __restrict__ out) {
  // 8 regions x 64 rows x 36 uints = 73728 B; h1 phase uses first 65536 B.
  __shared__ __align__(16) ushort_t h1s[36864];
  __shared__ float bi2s[512];
  __shared__ float ab[64];
  __shared__ float bi3s[64];

  int b = blockIdx.x, t = threadIdx.x;
  int w = t >> 6, l = t & 63;
  int l31 = l & 31, hi = l >> 5;

  bi2s[t] = bi2[t];
  if (t < 64) { ab[t] = a_bits[b * 64 + t]; bi3s[t] = bi3[t]; }

  // ---- phase 0: h1[64][512] = relu(sp[b] + pos) -> LDS bf16, swizzled, ONCE ----
  {
    const float* sprow = sp + (size_t)b * 512 + l * 8;
    float4 s0 = *(const float4*)(sprow);
    float4 s1 = *(const float4*)(sprow + 4);
#pragma unroll
    for (int g = 0; g < 8; ++g) {
      int p = g * 8 + w;                    // wave w covers rows {w, 8+w, ..., 56+w}
      bf16x8 pr = *(const bf16x8*)(posTb + (size_t)p * 512 + l * 8);
      float v0 = fmaxf(s0.x + bf2f(pr[0]), 0.f), v1 = fmaxf(s0.y + bf2f(pr[1]), 0.f);
      float v2 = fmaxf(s0.z + bf2f(pr[2]), 0.f), v3 = fmaxf(s0.w + bf2f(pr[3]), 0.f);
      float v4 = fmaxf(s1.x + bf2f(pr[4]), 0.f), v5 = fmaxf(s1.y + bf2f(pr[5]), 0.f);
      float v6 = fmaxf(s1.z + bf2f(pr[6]), 0.f), v7 = fmaxf(s1.w + bf2f(pr[7]), 0.f);
      uint4 pk;
      pk.x = pack2bf(v0, v1); pk.y = pack2bf(v2, v3);
      pk.z = pack2bf(v4, v5); pk.w = pack2bf(v6, v7);
      *(uint4*)((char*)h1s + ((p * 1024 + l * 16) ^ ((p & 15) << 4))) = pk;
    }
  }
  __syncthreads();

  // ---- GEMM1: mfma(Wi2, h1) ; 32x32x16, depth-4 B prefetch, barrier-free ----
  f32x16 acc[2][2];   // acc[mc][np]: reg<->c (c-tile mc), lane<->p (p-tile np)
#pragma unroll
  for (int mc = 0; mc < 2; ++mc)
#pragma unroll
    for (int np = 0; np < 2; ++np)
#pragma unroll
      for (int r = 0; r < 16; ++r) acc[mc][np][r] = 0.f;

  {
    const bf16x8* bbase = (const bf16x8*)Wi2f32 + ((size_t)(2 * w) * 64 + l);
    bf16x8 wf[4][2];
#pragma unroll
    for (int d = 0; d < 4; ++d) {
      wf[d][0] = bbase[(size_t)d * 1024];
      wf[d][1] = bbase[(size_t)d * 1024 + 64];
    }
    for (int kb = 0; kb < 8; ++kb) {
#pragma unroll
      for (int d = 0; d < 4; ++d) {
        int ks = kb * 4 + d;
        bf16x8 w0 = wf[d][0], w1 = wf[d][1];
        if (kb < 7) {
          wf[d][0] = bbase[(size_t)(ks + 4) * 1024];
          wf[d][1] = bbase[(size_t)(ks + 4) * 1024 + 64];
        }
        int row0 = l31, row1 = 32 + l31;
        bf16x8 h0 = *(const bf16x8*)((char*)h1s + ((row0 * 1024 + ks * 32 + hi * 16) ^ ((row0 & 15) << 4)));
        bf16x8 h1v = *(const bf16x8*)((char*)h1s + ((row1 * 1024 + ks * 32 + hi * 16) ^ ((row1 & 15) << 4)));
        acc[0][0] = __builtin_amdgcn_mfma_f32_32x32x16_bf16(w0, h0, acc[0][0], 0, 0, 0);
        acc[0][1] = __builtin_amdgcn_mfma_f32_32x32x16_bf16(w0, h1v, acc[0][1], 0, 0, 0);
        acc[1][0] = __builtin_amdgcn_mfma_f32_32x32x16_bf16(w1, h0, acc[1][0], 0, 0, 0);
        acc[1][1] = __builtin_amdgcn_mfma_f32_32x32x16_bf16(w1, h1v, acc[1][1], 0, 0, 0);
      }
    }
  }

  // ---- h2 = relu(acc + bi2), pack to bf16 A-frags in regs (layout verified R8) ----
  bf16x8 pkf[2][2][2];   // [np][mc][h]
#pragma unroll
  for (int mc = 0; mc < 2; ++mc) {
    float bia[16];
#pragma unroll
    for (int rq = 0; rq < 4; ++rq) {
      int c0 = w * 64 + mc * 32 + 8 * rq + 4 * hi;
      float4 bi4 = *(const float4*)(bi2s + c0);
      bia[4 * rq + 0] = bi4.x; bia[4 * rq + 1] = bi4.y;
      bia[4 * rq + 2] = bi4.z; bia[4 * rq + 3] = bi4.w;
    }
#pragma unroll
    for (int np = 0; np < 2; ++np) {
      float hv[16];
#pragma unroll
      for (int r = 0; r < 16; ++r) hv[r] = fmaxf(acc[mc][np][r] + bia[r], 0.f);
#pragma unroll
      for (int h = 0; h < 2; ++h) {
        unsigned d0 = pack2bf(hv[8 * h + 0], hv[8 * h + 1]);
        unsigned d1 = pack2bf(hv[8 * h + 2], hv[8 * h + 3]);
        unsigned d2 = pack2bf(hv[8 * h + 4], hv[8 * h + 5]);
        unsigned d3 = pack2bf(hv[8 * h + 6], hv[8 * h + 7]);
        union { unsigned u[4]; bf16x8 v; } cv;
        cv.u[0] = d0; cv.u[1] = d1; cv.u[2] = d2; cv.u[3] = d3;
        pkf[np][mc][h] = cv.v;
      }
    }
  }
  __syncthreads();   // all waves done reading h1s -> safe to reuse as partials

  // ---- GEMM2: partial logits over this wave's 64-c chunk, fully in-reg ----
  f32x16 l00, l01, l10, l11;
#pragma unroll
  for (int r = 0; r < 16; ++r) { l00[r] = 0.f; l01[r] = 0.f; l10[r] = 0.f; l11[r] = 0.f; }
  {
    const bf16x8* gbase = (const bf16x8*)Wi3g + ((size_t)w * 8 * 64 + l);
#pragma unroll
    for (int mc = 0; mc < 2; ++mc) {
#pragma unroll
      for (int h = 0; h < 2; ++h) {
        bf16x8 g0 = gbase[((mc * 2 + h) * 2 + 0) * 64];
        bf16x8 g1 = gbase[((mc * 2 + h) * 2 + 1) * 64];
        l00 = __builtin_amdgcn_mfma_f32_32x32x16_bf16(pkf[0][mc][h], g0, l00, 0, 0, 0);
        l01 = __builtin_amdgcn_mfma_f32_32x32x16_bf16(pkf[0][mc][h], g1, l01, 0, 0, 0);
        l10 = __builtin_amdgcn_mfma_f32_32x32x16_bf16(pkf[1][mc][h], g0, l10, 0, 0, 0);
        l11 = __builtin_amdgcn_mfma_f32_32x32x16_bf16(pkf[1][mc][h], g1, l11, 0, 0, 0);
      }
    }
  }

  // ---- pair-packed partial store: Pu_w[p*36 + q] = (P[p][q], P[p][q+32]) ----
  {
    unsigned* Pu = (unsigned*)h1s + (size_t)w * 2304;   // 64*36 uints per wave
#pragma unroll
    for (int r = 0; r < 16; ++r) {
      int p0 = (r & 3) + 8 * (r >> 2) + 4 * hi;
      int p1 = p0 + 32;
      Pu[p0 * 36 + l31] = pack2bf(l00[r], l01[r]);
      Pu[p1 * 36 + l31] = pack2bf(l10[r], l11[r]);
    }
  }
  __syncthreads();

  // ---- max-free softmax + gather: thread (p=t>>3, jo=t&7) sums 8 regions ----
  {
    int p = t >> 3, jo = t & 7;
    float slo[4] = {0.f, 0.f, 0.f, 0.f};
    float shi[4] = {0.f, 0.f, 0.f, 0.f};
#pragma unroll
    for (int wr = 0; wr < 8; ++wr) {
      const unsigned* Pu = (const unsigned*)h1s + (size_t)wr * 2304 + p * 36 + jo;
#pragma unroll
      for (int k = 0; k < 4; ++k) {
        unsigned v = Pu[8 * k];
        slo[k] += __uint_as_float(v << 16);
        shi[k] += __uint_as_float(v & 0xFFFF0000u);
      }
    }
    float s = 0.f, g = 0.f;
#pragma unroll
    for (int k = 0; k < 4; ++k) {
      int c = jo + 8 * k;
      float e0 = __expf(slo[k] + bi3s[c]);
      float e1 = __expf(shi[k] + bi3s[c + 32]);
      s += e0 + e1;
      g += e0 * ab[c] + e1 * ab[c + 32];
    }
#pragma unroll
    for (int mm = 4; mm >= 1; mm >>= 1) { s += __shfl_xor(s, mm); g += __shfl_xor(g, mm); }
    if (jo == 0) out[b * 64 + p] = g / s;
  }
}

extern "C" void kernel_launch(void* const* d_in, const int* in_sizes, int n_in,
                              void* d_out, int out_size, void* d_ws, size_t ws_size,
                              hipStream_t stream) {
  const float* a_bits     = (const float*)d_in[0];
  const float* shift_bits = (const float*)d_in[1];
  const float* W1  = (const float*)d_in[2];
  const float* b1  = (const float*)d_in[3];
  const float* g1  = (const float*)d_in[4];
  const float* be1 = (const float*)d_in[5];
  const float* W2  = (const float*)d_in[6];
  const float* b2  = (const float*)d_in[7];
  const float* g2  = (const float*)d_in[8];
  const float* be2 = (const float*)d_in[9];
  const float* W3  = (const float*)d_in[10];
  const float* b3  = (const float*)d_in[11];
  const float* Wi1 = (const float*)d_in[12];
  const float* bi1 = (const float*)d_in[13];
  const float* Wi2 = (const float*)d_in[14];
  const float* bi2 = (const float*)d_in[15];
  const float* Wi3 = (const float*)d_in[16];
  const float* bi3 = (const float*)d_in[17];
  float* out = (float*)d_out;

  // ws layout: sp fp32 [B][512] (8MB) | W2f (512KB) | W1b (64KB) | W3b (64KB)
  //            | Wi1sb (64KB) | Wi1posTb bf16 (64KB) | Wi2f32 (512KB) | Wi3g (64KB)
  float* sp = (float*)d_ws;
  ushort_t* W2f = (ushort_t*)((char*)d_ws + (size_t)B_N * HID * 4);
  ushort_t* W1b = W2f + 512 * 512;
  ushort_t* W3b = W1b + 512 * 64;
  ushort_t* Wi1sb = W3b + 64 * 512;
  ushort_t* Wi1posTb = Wi1sb + 512 * 64;
  ushort_t* Wi2f32 = Wi1posTb + 64 * 512;
  ushort_t* Wi3g = Wi2f32 + 512 * 512;

  prep_kernel<<<1024, 256, 0, stream>>>(Wi2, Wi3, Wi1, W1, W2, W3,
                                        Wi1posTb, W1b, W2f, W3b, Wi1sb, Wi2f32, Wi3g);
  shift3_kernel<<<B_N / BT, 512, 0, stream>>>(shift_bits, W1b, b1, g1, be1,
                                              W2f, b2, g2, be2, W3b, b3, Wi1sb, bi1, sp);
  big13_kernel<<<B_N, 512, 0, stream>>>(a_bits, sp, Wi1posTb, Wi2f32, Wi3g, bi2, bi3, out);
}